// Round 13
// baseline (421.831 us; speedup 1.0000x reference)
//
#include <hip/hip_runtime.h>
#include <hip/hip_fp16.h>
#include <math.h>
#include <type_traits>

// ---------------------------------------------------------------------------
// GATv2 x2 layers.
//   - CSR-by-dst via two-level counting sort (r7 lesson: direct scatter =
//     8x HBM write amplification; bucket sort buys L2 write locality).
//   - r13: launch-count 13 -> 10. partition absorbs bucket_scan (redundant
//     LDS scan of bcnt per block; bcur is a zeroed relative cursor) and
//     dst_hist (global atomicAdd on cnt[dst] -- L2-resident, r7-proven
//     cheap). scan3 absorbs scan2 (redundant LDS scan of bsum).
//     r9 crash class (last-block device sync, punned __half[8]) excluded.
//   - GEMMs on the MATRIX pipe: fp16 MFMA 16x16x32, fp32 accumulate.
//     r11 shape (4 waves x 4 col-tiles) -- r12 showed more waves/lower VGPR
//     HURTS (not latency-bound); r8 showed stores aren't the limiter.
//     Templated input: layer1 fp32, layer2 fp16 h1 (bit-identical, -25.6MB).
//   - Aggregation: EXACT round-1 form (proven 68.5us @ 89% VALUBusy):
//     one wave per node, 4 edges/iter, records 4 ahead / gathers 2 ahead,
//     dynamic loop, cvt_h2+fmaf body (r2-r5: asm/unroll degrade scheduling).
// ---------------------------------------------------------------------------

typedef _Float16 half8 __attribute__((ext_vector_type(8)));
typedef float floatx4 __attribute__((ext_vector_type(4)));

__global__ __launch_bounds__(256) void bucket_hist_sum(
    const int* __restrict__ dst, const float* __restrict__ ew,
    int* __restrict__ bcnt, float* __restrict__ sumbuf, int E) {
    __shared__ int h[256];
    h[threadIdx.x] = 0;
    __syncthreads();
    float s = 0.f;
    for (int i = blockIdx.x * blockDim.x + threadIdx.x; i < E; i += gridDim.x * blockDim.x) {
        atomicAdd(&h[dst[i] >> 8], 1);
        s += ew[i];
    }
#pragma unroll
    for (int off = 1; off <= 32; off <<= 1)
        s += __shfl_xor(s, off, 64);
    if ((threadIdx.x & 63) == 0)
        atomicAdd(sumbuf, s);
    __syncthreads();
    int v = h[threadIdx.x];
    if (v) atomicAdd(&bcnt[threadIdx.x], v);
}

// Partition edges into 256-node buckets. Absorbs the old bucket_scan (each
// block redundantly scans bcnt in LDS; bcur is a ZERO-based relative cursor)
// and dst_hist (per-node degree via global atomics on L2-resident cnt).
// Block 0 publishes bbase for refine (read only by later launches).
__global__ __launch_bounds__(256) void partition_kernel(
    const int* __restrict__ src, const int* __restrict__ dst, const float* __restrict__ ew,
    const int* __restrict__ bcnt, int* __restrict__ bcur, int* __restrict__ bbase,
    int* __restrict__ cnt, int2* __restrict__ srec, int E, int NBK) {
    __shared__ int ex[256];
    __shared__ int h[256];
    __shared__ int gb[256];
    const int t = threadIdx.x;

    // redundant exclusive scan of bcnt (replaces bucket_scan kernel)
    int v = (t < NBK) ? bcnt[t] : 0;
    ex[t] = v;
    __syncthreads();
    for (int off = 1; off < 256; off <<= 1) {
        int y = 0;
        if (t >= off) y = ex[t - off];
        __syncthreads();
        ex[t] += y;
        __syncthreads();
    }
    const int exbase = ex[t] - v;              // exclusive scan value for bucket t
    if (blockIdx.x == 0 && t <= NBK) bbase[t] = exbase;

    h[t] = 0;
    __syncthreads();
    const int base = blockIdx.x * 2048;
    int d[8], sv[8];
    float wv[8];
#pragma unroll
    for (int j = 0; j < 8; j++) {
        int i = base + t + j * 256;
        if (i < E) {
            d[j] = dst[i];
            sv[j] = src[i];
            wv[j] = ew[i];
            atomicAdd(&h[d[j] >> 8], 1);
            atomicAdd(&cnt[d[j]], 1);          // per-node degree (was dst_hist)
        } else {
            d[j] = -1;
        }
    }
    __syncthreads();
    int cntt = h[t];
    if (cntt) gb[t] = exbase + atomicAdd(&bcur[t], cntt);
    h[t] = 0;
    __syncthreads();
#pragma unroll
    for (int j = 0; j < 8; j++) {
        if (d[j] >= 0) {
            int b = d[j] >> 8;
            int r = atomicAdd(&h[b], 1);
            int pos = gb[b] + r;
            // pack src (bits 0..19) | (dst&255) << 20
            srec[pos] = make_int2(sv[j] | ((d[j] & 255) << 20), __float_as_int(wv[j]));
        }
    }
}

__global__ void scan1_kernel(const int* __restrict__ cnt, int* __restrict__ rowp,
                             int* __restrict__ bsum, int N) {
    __shared__ int sh[256];
    int i = blockIdx.x * 256 + threadIdx.x;
    int v = (i < N) ? (cnt[i] + 1) : 0;
    sh[threadIdx.x] = v;
    __syncthreads();
    for (int off = 1; off < 256; off <<= 1) {
        int y = 0;
        if ((int)threadIdx.x >= off) y = sh[threadIdx.x - off];
        __syncthreads();
        sh[threadIdx.x] += y;
        __syncthreads();
    }
    int incl = sh[threadIdx.x];
    if (i < N) rowp[i] = incl - v;
    if (threadIdx.x == 255) bsum[blockIdx.x] = incl;
}

// Finalize rowp + write self-loops. Absorbs scan2: each block redundantly
// scans the raw per-block sums (nb <= 256) in LDS.
__global__ void scan3_kernel(int* __restrict__ rowp, const int* __restrict__ bsum,
                             const int* __restrict__ cnt, const float* __restrict__ sumbuf,
                             int2* __restrict__ crec, int N, int E, int nb) {
    __shared__ int sh[256];
    const int t = threadIdx.x;
    int v = (t < nb) ? bsum[t] : 0;
    sh[t] = v;
    __syncthreads();
    for (int off = 1; off < 256; off <<= 1) {
        int y = 0;
        if (t >= off) y = sh[t - off];
        __syncthreads();
        sh[t] += y;
        __syncthreads();
    }
    int boff = sh[blockIdx.x] - bsum[blockIdx.x];   // exclusive offset of this block
    int i = blockIdx.x * 256 + t;
    if (i < N) {
        int rp = rowp[i] + boff;
        rowp[i] = rp;
        crec[rp + cnt[i]] = make_int2(i, __float_as_int(sumbuf[0] * (1.0f / (float)E)));
    }
    if (i == 0) rowp[N] = E + N;
}

__global__ __launch_bounds__(1024) void refine_kernel(
    const int2* __restrict__ srec, const int* __restrict__ bbase,
    const int* __restrict__ rowp, int2* __restrict__ crec, int N) {
    __shared__ int cur[256];
    const int t = threadIdx.x;
    const int b = blockIdx.x;
    if (t < 256) {
        int node = (b << 8) + t;
        cur[t] = (node < N) ? rowp[node] : 0;
    }
    __syncthreads();
    const int e0 = bbase[b], e1 = bbase[b + 1];
    for (int i = e0 + t; i < e1; i += 1024) {
        int2 rec = srec[i];
        int dlow = (rec.x >> 20) & 255;
        int pos = atomicAdd(&cur[dlow], 1);
        crec[pos] = make_int2(rec.x & 0xFFFFF, rec.y);
    }
}

// ---------------------------------------------------------------------------
// Pre-pack BOTH layers' W = [Wa | Wb] into fragment-ordered fp16 (one launch)
// and zero bcnt[0..259], bcur[0..259], cnt[0..N).
// ---------------------------------------------------------------------------
__global__ __launch_bounds__(256) void prep_w2_kernel(
    const float* __restrict__ Wa1, const float* __restrict__ Wb1,
    const float* __restrict__ Wa2, const float* __restrict__ Wb2,
    _Float16* __restrict__ Wh1, _Float16* __restrict__ Wh2,
    int* __restrict__ bcnt, int* __restrict__ bcur, int* __restrict__ cnt, int N) {
    const int bid = blockIdx.x;                 // 0..255
    if (bid == 0 && threadIdx.x < 260) bcnt[threadIdx.x] = 0;
    if (bid == 1 && threadIdx.x < 260) bcur[threadIdx.x] = 0;
    int zi = bid * 256 + threadIdx.x;
    if (zi < N) cnt[zi] = 0;
    const int sel = bid >> 7;
    const float* Wa = sel ? Wa2 : Wa1;
    const float* Wb = sel ? Wb2 : Wb1;
    _Float16* Wh = sel ? Wh2 : Wh1;
    int tid = (bid & 127) * 256 + threadIdx.x;  // 0 .. 32767
    int j = tid & 7;
    int lane = (tid >> 3) & 63;
    int f = tid >> 9;                           // 0..63
    int kk = f & 3;
    int ct = f >> 2;                            // 0..15
    int col = ct * 16 + (lane & 15);
    int k = kk * 32 + ((lane >> 4) << 3) + j;
    float v = (col < 128) ? Wa[k * 128 + col] : Wb[k * 128 + (col - 128)];
    Wh[tid] = (_Float16)v;
}

// ---------------------------------------------------------------------------
// Dual GEMM on the matrix pipe: Yh = half(X@Wa) [Nx128], Yb = X@Wb [Nx128].
// Templated input T: fp32 (layer 1, converted during staging) or fp16
// (layer 2, straight copy -- numerically identical, half the traffic).
// Block: 64 rows x 256 cols, 4 waves x 4 col-tiles (r11 shape; r12 showed
// 8x2 lower-VGPR variant is slightly worse). Swapped operands (D = W^T X^T);
// r6 epilogue (r8 lesson: LDS-transpose store-coalescing is a net loss).
// ---------------------------------------------------------------------------
template <typename T>
__global__ __launch_bounds__(256) void gemm_mfma_kernel(
    const T* __restrict__ X, const _Float16* __restrict__ Wh,
    __half* __restrict__ Yh, float* __restrict__ Yb, int N) {
    __shared__ _Float16 Xs[64 * 128];            // 16 KB, swizzled
    const int tid = threadIdx.x;
    const int lane = tid & 63;
    const int w = tid >> 6;
    const int rb = blockIdx.x * 64;

    // W fragments -> registers (16 x coalesced 16B/lane loads)
    half8 wf[4][4];
#pragma unroll
    for (int ct = 0; ct < 4; ct++)
#pragma unroll
        for (int kk = 0; kk < 4; kk++)
            wf[ct][kk] = *(const half8*)(Wh + (size_t)(((w * 4 + ct) * 4 + kk) * 512 + lane * 8));

    // Stage X tile into swizzled LDS.
    if constexpr (std::is_same<T, float>::value) {
        // fp32 -> fp16 convert; 2048 float4-chunks / 256 threads.
#pragma unroll
        for (int it = 0; it < 8; it++) {
            int c = it * 256 + tid;
            int row = c >> 5;
            int f4 = c & 31;
            float4 v = make_float4(0.f, 0.f, 0.f, 0.f);
            if (rb + row < N)
                v = ((const float4*)X)[(size_t)(rb + row) * 32 + f4];
            _Float16 h[4] = {(_Float16)v.x, (_Float16)v.y, (_Float16)v.z, (_Float16)v.w};
            int byteoff = row * 256 + ((f4 * 8) ^ ((row & 7) << 4));
            *(uint2*)((char*)Xs + byteoff) = *(uint2*)h;
        }
    } else {
        // fp16 straight copy; 1024 int4-chunks / 256 threads.
#pragma unroll
        for (int it = 0; it < 4; it++) {
            int c = it * 256 + tid;
            int row = c >> 4;
            int f16 = c & 15;
            int4 v = make_int4(0, 0, 0, 0);
            if (rb + row < N)
                v = ((const int4*)X)[(size_t)(rb + row) * 16 + f16];
            int byteoff = row * 256 + ((f16 * 16) ^ ((row & 7) << 4));
            *(int4*)((char*)Xs + byteoff) = v;
        }
    }
    __syncthreads();

    floatx4 acc[4][4];
#pragma unroll
    for (int ct = 0; ct < 4; ct++)
#pragma unroll
        for (int rt = 0; rt < 4; rt++)
            acc[ct][rt] = (floatx4){0.f, 0.f, 0.f, 0.f};

#pragma unroll
    for (int kk = 0; kk < 4; kk++) {
        half8 xf[4];
#pragma unroll
        for (int rt = 0; rt < 4; rt++) {
            int row = rt * 16 + (lane & 15);
            int kb = kk * 64 + ((lane >> 4) << 4);
            int off = row * 256 + (kb ^ ((row & 7) << 4));
            xf[rt] = *(const half8*)((const char*)Xs + off);
        }
#pragma unroll
        for (int ct = 0; ct < 4; ct++)
#pragma unroll
            for (int rt = 0; rt < 4; rt++)
                acc[ct][rt] = __builtin_amdgcn_mfma_f32_16x16x32_f16(
                    wf[ct][kk], xf[rt], acc[ct][rt], 0, 0, 0);
    }

    // Epilogue: lane owns row rb+rt*16+(lane&15), cols gct*16+(lane>>4)*4 ..+3
    const int rsub = lane & 15;
    const int c4 = (lane >> 4) << 2;
#pragma unroll
    for (int ct = 0; ct < 4; ct++) {
        int gct = w * 4 + ct;
#pragma unroll
        for (int rt = 0; rt < 4; rt++) {
            int row = rb + rt * 16 + rsub;
            if (row < N) {
                floatx4 a = acc[ct][rt];
                if (gct < 8) {
                    int col = gct * 16 + c4;
                    __half2 hp[2];
                    hp[0] = __floats2half2_rn(a[0], a[1]);
                    hp[1] = __floats2half2_rn(a[2], a[3]);
                    *(uint2*)(Yh + (size_t)row * 128 + col) = *(uint2*)hp;
                } else {
                    int col = (gct - 8) * 16 + c4;
                    *(float4*)(Yb + (size_t)row * 128 + col) =
                        make_float4(a[0], a[1], a[2], a[3]);
                }
            }
        }
    }
}

// DPP partial-sum step within quads on the VALU pipe.
template <int CTRL>
__device__ __forceinline__ float dpp_sum_step(float v) {
    int t = __builtin_amdgcn_update_dpp(0, __float_as_int(v), CTRL, 0xF, 0xF, true);
    return v + __int_as_float(t);
}

__device__ __forceinline__ float2 cvt_h2(unsigned u) {
    __half2 h = *(__half2*)&u;
    return __half22float2(h);
}

// One wave per node; 4 edges/iteration.
// lane l: g=l>>4 (edge slot), q=l&15 -> channels 8q..8q+7 (head q>>2).
// Pipeline: records 4 iters ahead, gathers 2 iters ahead.  (round-1 exact)
// mode 0: ELU output stored as fp16 (h1), packed via __half2 pairs;
// mode 1: fp32 final output.
__global__ __launch_bounds__(256) void agg_kernel(
    const __half* __restrict__ xlh, const float* __restrict__ xr,
    const int* __restrict__ rowp, const int2* __restrict__ crec,
    const float* __restrict__ We, const float* __restrict__ att, const float* __restrict__ bias,
    void* __restrict__ out, int N, int mode) {
    const int wid = threadIdx.x >> 6;
    const int lane = threadIdx.x & 63;
    const int n = blockIdx.x * 4 + wid;
    if (n >= N) return;
    const int g = lane >> 4;
    const int q = lane & 15;
    const int c0 = q << 3;                         // channel base, 8 per lane
    const float LOG2E = 1.4426950408889634f;

    float we[8], xv[8], at6[8], at4[8];
    {
        float4 wA = *(const float4*)(We + c0);
        float4 wB = *(const float4*)(We + c0 + 4);
        we[0]=wA.x; we[1]=wA.y; we[2]=wA.z; we[3]=wA.w;
        we[4]=wB.x; we[5]=wB.y; we[6]=wB.z; we[7]=wB.w;
        float4 rA = *(const float4*)(xr + (size_t)n * 128 + c0);
        float4 rB = *(const float4*)(xr + (size_t)n * 128 + c0 + 4);
        xv[0]=rA.x; xv[1]=rA.y; xv[2]=rA.z; xv[3]=rA.w;
        xv[4]=rB.x; xv[5]=rB.y; xv[6]=rB.z; xv[7]=rB.w;
        float4 aA = *(const float4*)(att + c0);
        float4 aB = *(const float4*)(att + c0 + 4);
        float av[8] = {aA.x, aA.y, aA.z, aA.w, aB.x, aB.y, aB.z, aB.w};
#pragma unroll
        for (int c = 0; c < 8; c++) {
            at6[c] = 0.6f * LOG2E * av[c];
            at4[c] = 0.4f * LOG2E * av[c];
        }
    }

    float acc[8];
#pragma unroll
    for (int c = 0; c < 8; c++) acc[c] = 0.f;
    float l0 = 0.f;

    const int e0 = __builtin_amdgcn_readfirstlane(rowp[n]);
    const int e1 = __builtin_amdgcn_readfirstlane(rowp[n + 1]);
    const int cnt = e1 - e0;
    const int T = (cnt + 3) >> 2;

    auto recload = [&](int i) -> int2 {
        int idx = e0 + (i << 2) + g;
        idx = (idx < e1 - 1) ? idx : (e1 - 1);     // clamp (always valid)
        return crec[idx];
    };
    auto gatherx = [&](int s) -> int4 {            // 8 halves = 16B
        return *(const int4*)(xlh + (size_t)s * 128 + c0);
    };
    auto process = [&](int4 xh, float w, bool valid) {
        float2 x01 = cvt_h2(xh.x), x23 = cvt_h2(xh.y);
        float2 x45 = cvt_h2(xh.z), x67 = cvt_h2(xh.w);
        float xs[8] = {x01.x, x01.y, x23.x, x23.y, x45.x, x45.y, x67.x, x67.y};
        float p = 0.f;
#pragma unroll
        for (int c = 0; c < 8; c++) {
            float z = xs[c] + fmaf(w, we[c], xv[c]);
            p = fmaf(at6[c], z, fmaf(at4[c], fabsf(z), p));  // leaky folded
        }
        p = dpp_sum_step<0xB1>(p);    // quad_perm [1,0,3,2]
        p = dpp_sum_step<0x4E>(p);    // quad_perm [2,3,0,1]  -> per-head sum
        float qe = valid ? __builtin_amdgcn_exp2f(p) : 0.f;
        l0 += qe;
#pragma unroll
        for (int c = 0; c < 8; c++) acc[c] = fmaf(qe, xs[c], acc[c]);
    };

    // rolling pipeline: records 4 iters ahead, gathers 2 ahead
    int2 r0 = recload(0), r1 = recload(1), r2 = recload(2), r3 = recload(3);
    int4 x0 = gatherx(r0.x), x1 = gatherx(r1.x);
    for (int i = 0; i < T; ++i) {
        int2 r4 = recload(i + 4);
        int4 x2 = gatherx(r2.x);
        process(x0, __int_as_float(r0.y), (e0 + (i << 2) + g) < e1);
        r0 = r1; r1 = r2; r2 = r3; r3 = r4;
        x0 = x1; x1 = x2;
    }

    // combine the 4 edge groups
    l0 += __shfl_xor(l0, 16, 64);
    l0 += __shfl_xor(l0, 32, 64);
#pragma unroll
    for (int c = 0; c < 8; c++) {
        acc[c] += __shfl_xor(acc[c], 16, 64);
        acc[c] += __shfl_xor(acc[c], 32, 64);
    }
    float rdenom = 1.0f / (l0 + 1e-16f);
    float r[8];
#pragma unroll
    for (int c = 0; c < 8; c++) r[c] = acc[c] * rdenom;

    if (mode == 0) {
        if (g == 0) {
            float4 bA = *(const float4*)(bias + c0);
            float4 bB = *(const float4*)(bias + c0 + 4);
            float bv[8] = {bA.x, bA.y, bA.z, bA.w, bB.x, bB.y, bB.z, bB.w};
            float o[8];
#pragma unroll
            for (int c = 0; c < 8; c++) {
                float v = r[c] + bv[c];
                o[c] = (v > 0.f) ? v : (__expf(v) - 1.f);   // ELU
            }
            __half2 p0 = __floats2half2_rn(o[0], o[1]);
            __half2 p1 = __floats2half2_rn(o[2], o[3]);
            __half2 p2 = __floats2half2_rn(o[4], o[5]);
            __half2 p3 = __floats2half2_rn(o[6], o[7]);
            int4 pk = make_int4(*(int*)&p0, *(int*)&p1, *(int*)&p2, *(int*)&p3);
            *(int4*)((__half*)out + (size_t)n * 128 + c0) = pk;
        }
    } else {
#pragma unroll
        for (int c = 0; c < 8; c++) {
            r[c] += __shfl_xor(r[c], 4, 64);
            r[c] += __shfl_xor(r[c], 8, 64);
        }
        if (lane < 4) {
            int w0 = lane << 3;
            float4 bA = *(const float4*)(bias + w0);
            float4 bB = *(const float4*)(bias + w0 + 4);
            float bv[8] = {bA.x, bA.y, bA.z, bA.w, bB.x, bB.y, bB.z, bB.w};
            float o[8];
#pragma unroll
            for (int c = 0; c < 8; c++) o[c] = 0.25f * r[c] + bv[c];
            float* op = (float*)out + (size_t)n * 32 + w0;
            *(float4*)op       = make_float4(o[0], o[1], o[2], o[3]);
            *(float4*)(op + 4) = make_float4(o[4], o[5], o[6], o[7]);
        }
    }
}

extern "C" void kernel_launch(void* const* d_in, const int* in_sizes, int n_in,
                              void* d_out, int out_size, void* d_ws, size_t ws_size,
                              hipStream_t stream) {
    const float* x    = (const float*)d_in[0];
    const int*  eidx  = (const int*)d_in[1];
    const float* ew   = (const float*)d_in[2];
    const float* Wl1  = (const float*)d_in[3];
    const float* Wr1  = (const float*)d_in[4];
    const float* We1  = (const float*)d_in[5];
    const float* att1 = (const float*)d_in[6];
    const float* b1   = (const float*)d_in[7];
    const float* Wl2  = (const float*)d_in[8];
    const float* Wr2  = (const float*)d_in[9];
    const float* We2  = (const float*)d_in[10];
    const float* att2 = (const float*)d_in[11];
    const float* b2   = (const float*)d_in[12];

    const int N = in_sizes[0] / 128;
    const int E = in_sizes[1] / 2;
    const int* src = eidx;
    const int* dst = eidx + E;
    const int NBK = (N + 255) >> 8;

    char* p = (char*)d_ws;
    auto alloc = [&](size_t bytes) -> void* {
        void* r = (void*)p;
        p += (bytes + 255) & ~(size_t)255;
        return r;
    };
    __half* xlh   = (__half*)alloc((size_t)N * 128 * sizeof(__half));
    float* xr     = (float*)alloc((size_t)N * 128 * sizeof(float));
    __half* h1h   = (__half*)alloc((size_t)N * 128 * sizeof(float));  // fp16 used; fp32-sized (srec alias)
    int2*  crec   = (int2*)alloc((size_t)(E + N + 64) * sizeof(int2));
    int*   rowp   = (int*)alloc((size_t)(N + 1) * sizeof(int));
    int*   cnt    = (int*)alloc((size_t)N * sizeof(int));
    int*   bcnt   = (int*)alloc(260 * sizeof(int));
    float* sumbuf = (float*)(bcnt + 256);
    int*   bbase  = (int*)alloc(260 * sizeof(int));
    int*   bcur   = (int*)alloc(260 * sizeof(int));
    int*   bsum   = (int*)alloc(256 * sizeof(int));
    _Float16* Wh1 = (_Float16*)alloc(32768 * sizeof(_Float16));
    _Float16* Wh2 = (_Float16*)alloc(32768 * sizeof(_Float16));
    int2*  srec   = (int2*)h1h;                     // staging aliased into h1

    // weight pre-pack (both layers) + zeroing of bcnt/sumbuf/bcur/cnt
    prep_w2_kernel<<<256, 256, 0, stream>>>(Wl1, Wr1, Wl2, Wr2, Wh1, Wh2,
                                            bcnt, bcur, cnt, N);

    bucket_hist_sum<<<1024, 256, 0, stream>>>(dst, ew, bcnt, sumbuf, E);
    partition_kernel<<<(E + 2047) / 2048, 256, 0, stream>>>(
        src, dst, ew, bcnt, bcur, bbase, cnt, srec, E, NBK);

    int nb = (N + 255) / 256;
    scan1_kernel<<<nb, 256, 0, stream>>>(cnt, rowp, bsum, N);
    scan3_kernel<<<nb, 256, 0, stream>>>(rowp, bsum, cnt, sumbuf, crec, N, E, nb);

    refine_kernel<<<NBK, 1024, 0, stream>>>(srec, bbase, rowp, crec, N);

    // Layer 1 (fp32 input)
    gemm_mfma_kernel<float><<<(N + 63) / 64, 256, 0, stream>>>(x, Wh1, xlh, xr, N);
    agg_kernel<<<(N + 3) / 4, 256, 0, stream>>>(xlh, xr, rowp, crec,
                                                We1, att1, b1, (void*)h1h, N, 0);
    // Layer 2 (fp16 input)
    gemm_mfma_kernel<_Float16><<<(N + 63) / 64, 256, 0, stream>>>(
        (const _Float16*)h1h, Wh2, xlh, xr, N);
    agg_kernel<<<(N + 3) / 4, 256, 0, stream>>>(xlh, xr, rowp, crec,
                                                We2, att2, b2, d_out, N, 1);
}

// Round 14
// 363.117 us; speedup vs baseline: 1.1617x; 1.1617x over previous
//
#include <hip/hip_runtime.h>
#include <hip/hip_fp16.h>
#include <math.h>
#include <type_traits>

// ---------------------------------------------------------------------------
// GATv2 x2 layers.
//   - CSR-by-dst via two-level counting sort (r7 lesson: direct scatter =
//     8x HBM write amplification; bucket sort buys L2 write locality).
//     r13 lesson: cnt[dst] GLOBAL atomics in partition = 94us latency-bound
//     disaster (VALUBusy 1.3%); per-node degree counting must stay
//     LDS-histogram (dst_hist). bucket_scan/scan2 merges kept (neutral).
//   - GEMMs on the MATRIX pipe: fp16 MFMA 16x16x32, fp32 accumulate.
//     r11 shape (4 waves x 4 col-tiles; r12: lower-VGPR variant worse).
//     Templated input: layer1 fp32, layer2 fp16 h1 (bit-identical, -25.6MB).
//   - Aggregation: EXACT round-1 form (proven 68.5us @ 89% VALUBusy):
//     one wave per node, 4 edges/iter, records 4 ahead / gathers 2 ahead,
//     dynamic loop, cvt_h2+fmaf body (r2-r5: asm/unroll degrade scheduling).
// ---------------------------------------------------------------------------

typedef _Float16 half8 __attribute__((ext_vector_type(8)));
typedef float floatx4 __attribute__((ext_vector_type(4)));

__global__ __launch_bounds__(256) void bucket_hist_sum(
    const int* __restrict__ dst, const float* __restrict__ ew,
    int* __restrict__ bcnt, float* __restrict__ sumbuf, int E) {
    __shared__ int h[256];
    h[threadIdx.x] = 0;
    __syncthreads();
    float s = 0.f;
    for (int i = blockIdx.x * blockDim.x + threadIdx.x; i < E; i += gridDim.x * blockDim.x) {
        atomicAdd(&h[dst[i] >> 8], 1);
        s += ew[i];
    }
#pragma unroll
    for (int off = 1; off <= 32; off <<= 1)
        s += __shfl_xor(s, off, 64);
    if ((threadIdx.x & 63) == 0)
        atomicAdd(sumbuf, s);
    __syncthreads();
    int v = h[threadIdx.x];
    if (v) atomicAdd(&bcnt[threadIdx.x], v);
}

// Partition edges into 256-node buckets. Absorbs bucket_scan (each block
// redundantly scans bcnt in LDS; bcur is a ZERO-based relative cursor).
// Block 0 publishes bbase for dst_hist/refine (read by later launches only).
__global__ __launch_bounds__(256) void partition_kernel(
    const int* __restrict__ src, const int* __restrict__ dst, const float* __restrict__ ew,
    const int* __restrict__ bcnt, int* __restrict__ bcur, int* __restrict__ bbase,
    int2* __restrict__ srec, int E, int NBK) {
    __shared__ int ex[256];
    __shared__ int h[256];
    __shared__ int gb[256];
    const int t = threadIdx.x;

    // redundant exclusive scan of bcnt (replaces bucket_scan kernel)
    int v = (t < NBK) ? bcnt[t] : 0;
    ex[t] = v;
    __syncthreads();
    for (int off = 1; off < 256; off <<= 1) {
        int y = 0;
        if (t >= off) y = ex[t - off];
        __syncthreads();
        ex[t] += y;
        __syncthreads();
    }
    const int exbase = ex[t] - v;              // exclusive scan value for bucket t
    if (blockIdx.x == 0 && t <= NBK) bbase[t] = exbase;

    h[t] = 0;
    __syncthreads();
    const int base = blockIdx.x * 2048;
    int d[8], sv[8];
    float wv[8];
#pragma unroll
    for (int j = 0; j < 8; j++) {
        int i = base + t + j * 256;
        if (i < E) {
            d[j] = dst[i];
            sv[j] = src[i];
            wv[j] = ew[i];
            atomicAdd(&h[d[j] >> 8], 1);
        } else {
            d[j] = -1;
        }
    }
    __syncthreads();
    int cntt = h[t];
    if (cntt) gb[t] = exbase + atomicAdd(&bcur[t], cntt);
    h[t] = 0;
    __syncthreads();
#pragma unroll
    for (int j = 0; j < 8; j++) {
        if (d[j] >= 0) {
            int b = d[j] >> 8;
            int r = atomicAdd(&h[b], 1);
            int pos = gb[b] + r;
            // pack src (bits 0..19) | (dst&255) << 20
            srec[pos] = make_int2(sv[j] | ((d[j] & 255) << 20), __float_as_int(wv[j]));
        }
    }
}

// Per-node degrees via bucket-local LDS histograms (r13 lesson: global
// atomics here are a latency-bound disaster; LDS is ~6x faster).
__global__ __launch_bounds__(1024) void dst_hist_kernel(
    const int2* __restrict__ srec, const int* __restrict__ bbase,
    int* __restrict__ cnt, int N) {
    __shared__ int h4[4][256];
    const int t = threadIdx.x;            // 0..1023
    const int grp = t >> 8, sub = t & 255;
    h4[grp][sub] = 0;
    __syncthreads();
    const int b = blockIdx.x;
    const int e0 = bbase[b], e1 = bbase[b + 1];
    for (int i = e0 + t; i < e1; i += 1024)
        atomicAdd(&h4[grp][(srec[i].x >> 20) & 255], 1);
    __syncthreads();
    if (t < 256) {
        int node = (b << 8) + t;
        if (node < N) cnt[node] = h4[0][t] + h4[1][t] + h4[2][t] + h4[3][t];
    }
}

__global__ void scan1_kernel(const int* __restrict__ cnt, int* __restrict__ rowp,
                             int* __restrict__ bsum, int N) {
    __shared__ int sh[256];
    int i = blockIdx.x * 256 + threadIdx.x;
    int v = (i < N) ? (cnt[i] + 1) : 0;
    sh[threadIdx.x] = v;
    __syncthreads();
    for (int off = 1; off < 256; off <<= 1) {
        int y = 0;
        if ((int)threadIdx.x >= off) y = sh[threadIdx.x - off];
        __syncthreads();
        sh[threadIdx.x] += y;
        __syncthreads();
    }
    int incl = sh[threadIdx.x];
    if (i < N) rowp[i] = incl - v;
    if (threadIdx.x == 255) bsum[blockIdx.x] = incl;
}

// Finalize rowp + write self-loops. Absorbs scan2: each block redundantly
// scans the raw per-block sums (nb <= 256) in LDS.
__global__ void scan3_kernel(int* __restrict__ rowp, const int* __restrict__ bsum,
                             const int* __restrict__ cnt, const float* __restrict__ sumbuf,
                             int2* __restrict__ crec, int N, int E, int nb) {
    __shared__ int sh[256];
    const int t = threadIdx.x;
    int v = (t < nb) ? bsum[t] : 0;
    sh[t] = v;
    __syncthreads();
    for (int off = 1; off < 256; off <<= 1) {
        int y = 0;
        if (t >= off) y = sh[t - off];
        __syncthreads();
        sh[t] += y;
        __syncthreads();
    }
    int boff = sh[blockIdx.x] - bsum[blockIdx.x];   // exclusive offset of this block
    int i = blockIdx.x * 256 + t;
    if (i < N) {
        int rp = rowp[i] + boff;
        rowp[i] = rp;
        crec[rp + cnt[i]] = make_int2(i, __float_as_int(sumbuf[0] * (1.0f / (float)E)));
    }
    if (i == 0) rowp[N] = E + N;
}

__global__ __launch_bounds__(1024) void refine_kernel(
    const int2* __restrict__ srec, const int* __restrict__ bbase,
    const int* __restrict__ rowp, int2* __restrict__ crec, int N) {
    __shared__ int cur[256];
    const int t = threadIdx.x;
    const int b = blockIdx.x;
    if (t < 256) {
        int node = (b << 8) + t;
        cur[t] = (node < N) ? rowp[node] : 0;
    }
    __syncthreads();
    const int e0 = bbase[b], e1 = bbase[b + 1];
    for (int i = e0 + t; i < e1; i += 1024) {
        int2 rec = srec[i];
        int dlow = (rec.x >> 20) & 255;
        int pos = atomicAdd(&cur[dlow], 1);
        crec[pos] = make_int2(rec.x & 0xFFFFF, rec.y);
    }
}

// ---------------------------------------------------------------------------
// Pre-pack BOTH layers' W = [Wa | Wb] into fragment-ordered fp16 (one launch)
// and zero bcnt[0..259] + bcur[0..259].
// ---------------------------------------------------------------------------
__global__ __launch_bounds__(256) void prep_w2_kernel(
    const float* __restrict__ Wa1, const float* __restrict__ Wb1,
    const float* __restrict__ Wa2, const float* __restrict__ Wb2,
    _Float16* __restrict__ Wh1, _Float16* __restrict__ Wh2,
    int* __restrict__ bcnt, int* __restrict__ bcur) {
    const int bid = blockIdx.x;                 // 0..255
    if (bid == 0 && threadIdx.x < 260) bcnt[threadIdx.x] = 0;
    if (bid == 1 && threadIdx.x < 260) bcur[threadIdx.x] = 0;
    const int sel = bid >> 7;
    const float* Wa = sel ? Wa2 : Wa1;
    const float* Wb = sel ? Wb2 : Wb1;
    _Float16* Wh = sel ? Wh2 : Wh1;
    int tid = (bid & 127) * 256 + threadIdx.x;  // 0 .. 32767
    int j = tid & 7;
    int lane = (tid >> 3) & 63;
    int f = tid >> 9;                           // 0..63
    int kk = f & 3;
    int ct = f >> 2;                            // 0..15
    int col = ct * 16 + (lane & 15);
    int k = kk * 32 + ((lane >> 4) << 3) + j;
    float v = (col < 128) ? Wa[k * 128 + col] : Wb[k * 128 + (col - 128)];
    Wh[tid] = (_Float16)v;
}

// ---------------------------------------------------------------------------
// Dual GEMM on the matrix pipe: Yh = half(X@Wa) [Nx128], Yb = X@Wb [Nx128].
// Templated input T: fp32 (layer 1, converted during staging) or fp16
// (layer 2, straight copy -- numerically identical, half the traffic).
// Block: 64 rows x 256 cols, 4 waves x 4 col-tiles (r11 shape; r12 showed
// 8x2 lower-VGPR variant is slightly worse). Swapped operands (D = W^T X^T);
// r6 epilogue (r8 lesson: LDS-transpose store-coalescing is a net loss).
// ---------------------------------------------------------------------------
template <typename T>
__global__ __launch_bounds__(256) void gemm_mfma_kernel(
    const T* __restrict__ X, const _Float16* __restrict__ Wh,
    __half* __restrict__ Yh, float* __restrict__ Yb, int N) {
    __shared__ _Float16 Xs[64 * 128];            // 16 KB, swizzled
    const int tid = threadIdx.x;
    const int lane = tid & 63;
    const int w = tid >> 6;
    const int rb = blockIdx.x * 64;

    // W fragments -> registers (16 x coalesced 16B/lane loads)
    half8 wf[4][4];
#pragma unroll
    for (int ct = 0; ct < 4; ct++)
#pragma unroll
        for (int kk = 0; kk < 4; kk++)
            wf[ct][kk] = *(const half8*)(Wh + (size_t)(((w * 4 + ct) * 4 + kk) * 512 + lane * 8));

    // Stage X tile into swizzled LDS.
    if constexpr (std::is_same<T, float>::value) {
        // fp32 -> fp16 convert; 2048 float4-chunks / 256 threads.
#pragma unroll
        for (int it = 0; it < 8; it++) {
            int c = it * 256 + tid;
            int row = c >> 5;
            int f4 = c & 31;
            float4 v = make_float4(0.f, 0.f, 0.f, 0.f);
            if (rb + row < N)
                v = ((const float4*)X)[(size_t)(rb + row) * 32 + f4];
            _Float16 h[4] = {(_Float16)v.x, (_Float16)v.y, (_Float16)v.z, (_Float16)v.w};
            int byteoff = row * 256 + ((f4 * 8) ^ ((row & 7) << 4));
            *(uint2*)((char*)Xs + byteoff) = *(uint2*)h;
        }
    } else {
        // fp16 straight copy; 1024 int4-chunks / 256 threads.
#pragma unroll
        for (int it = 0; it < 4; it++) {
            int c = it * 256 + tid;
            int row = c >> 4;
            int f16 = c & 15;
            int4 v = make_int4(0, 0, 0, 0);
            if (rb + row < N)
                v = ((const int4*)X)[(size_t)(rb + row) * 16 + f16];
            int byteoff = row * 256 + ((f16 * 16) ^ ((row & 7) << 4));
            *(int4*)((char*)Xs + byteoff) = v;
        }
    }
    __syncthreads();

    floatx4 acc[4][4];
#pragma unroll
    for (int ct = 0; ct < 4; ct++)
#pragma unroll
        for (int rt = 0; rt < 4; rt++)
            acc[ct][rt] = (floatx4){0.f, 0.f, 0.f, 0.f};

#pragma unroll
    for (int kk = 0; kk < 4; kk++) {
        half8 xf[4];
#pragma unroll
        for (int rt = 0; rt < 4; rt++) {
            int row = rt * 16 + (lane & 15);
            int kb = kk * 64 + ((lane >> 4) << 4);
            int off = row * 256 + (kb ^ ((row & 7) << 4));
            xf[rt] = *(const half8*)((const char*)Xs + off);
        }
#pragma unroll
        for (int ct = 0; ct < 4; ct++)
#pragma unroll
            for (int rt = 0; rt < 4; rt++)
                acc[ct][rt] = __builtin_amdgcn_mfma_f32_16x16x32_f16(
                    wf[ct][kk], xf[rt], acc[ct][rt], 0, 0, 0);
    }

    // Epilogue: lane owns row rb+rt*16+(lane&15), cols gct*16+(lane>>4)*4 ..+3
    const int rsub = lane & 15;
    const int c4 = (lane >> 4) << 2;
#pragma unroll
    for (int ct = 0; ct < 4; ct++) {
        int gct = w * 4 + ct;
#pragma unroll
        for (int rt = 0; rt < 4; rt++) {
            int row = rb + rt * 16 + rsub;
            if (row < N) {
                floatx4 a = acc[ct][rt];
                if (gct < 8) {
                    int col = gct * 16 + c4;
                    __half2 hp[2];
                    hp[0] = __floats2half2_rn(a[0], a[1]);
                    hp[1] = __floats2half2_rn(a[2], a[3]);
                    *(uint2*)(Yh + (size_t)row * 128 + col) = *(uint2*)hp;
                } else {
                    int col = (gct - 8) * 16 + c4;
                    *(float4*)(Yb + (size_t)row * 128 + col) =
                        make_float4(a[0], a[1], a[2], a[3]);
                }
            }
        }
    }
}

// DPP partial-sum step within quads on the VALU pipe.
template <int CTRL>
__device__ __forceinline__ float dpp_sum_step(float v) {
    int t = __builtin_amdgcn_update_dpp(0, __float_as_int(v), CTRL, 0xF, 0xF, true);
    return v + __int_as_float(t);
}

__device__ __forceinline__ float2 cvt_h2(unsigned u) {
    __half2 h = *(__half2*)&u;
    return __half22float2(h);
}

// One wave per node; 4 edges/iteration.
// lane l: g=l>>4 (edge slot), q=l&15 -> channels 8q..8q+7 (head q>>2).
// Pipeline: records 4 iters ahead, gathers 2 iters ahead.  (round-1 exact)
// mode 0: ELU output stored as fp16 (h1), packed via __half2 pairs;
// mode 1: fp32 final output.
__global__ __launch_bounds__(256) void agg_kernel(
    const __half* __restrict__ xlh, const float* __restrict__ xr,
    const int* __restrict__ rowp, const int2* __restrict__ crec,
    const float* __restrict__ We, const float* __restrict__ att, const float* __restrict__ bias,
    void* __restrict__ out, int N, int mode) {
    const int wid = threadIdx.x >> 6;
    const int lane = threadIdx.x & 63;
    const int n = blockIdx.x * 4 + wid;
    if (n >= N) return;
    const int g = lane >> 4;
    const int q = lane & 15;
    const int c0 = q << 3;                         // channel base, 8 per lane
    const float LOG2E = 1.4426950408889634f;

    float we[8], xv[8], at6[8], at4[8];
    {
        float4 wA = *(const float4*)(We + c0);
        float4 wB = *(const float4*)(We + c0 + 4);
        we[0]=wA.x; we[1]=wA.y; we[2]=wA.z; we[3]=wA.w;
        we[4]=wB.x; we[5]=wB.y; we[6]=wB.z; we[7]=wB.w;
        float4 rA = *(const float4*)(xr + (size_t)n * 128 + c0);
        float4 rB = *(const float4*)(xr + (size_t)n * 128 + c0 + 4);
        xv[0]=rA.x; xv[1]=rA.y; xv[2]=rA.z; xv[3]=rA.w;
        xv[4]=rB.x; xv[5]=rB.y; xv[6]=rB.z; xv[7]=rB.w;
        float4 aA = *(const float4*)(att + c0);
        float4 aB = *(const float4*)(att + c0 + 4);
        float av[8] = {aA.x, aA.y, aA.z, aA.w, aB.x, aB.y, aB.z, aB.w};
#pragma unroll
        for (int c = 0; c < 8; c++) {
            at6[c] = 0.6f * LOG2E * av[c];
            at4[c] = 0.4f * LOG2E * av[c];
        }
    }

    float acc[8];
#pragma unroll
    for (int c = 0; c < 8; c++) acc[c] = 0.f;
    float l0 = 0.f;

    const int e0 = __builtin_amdgcn_readfirstlane(rowp[n]);
    const int e1 = __builtin_amdgcn_readfirstlane(rowp[n + 1]);
    const int cnt = e1 - e0;
    const int T = (cnt + 3) >> 2;

    auto recload = [&](int i) -> int2 {
        int idx = e0 + (i << 2) + g;
        idx = (idx < e1 - 1) ? idx : (e1 - 1);     // clamp (always valid)
        return crec[idx];
    };
    auto gatherx = [&](int s) -> int4 {            // 8 halves = 16B
        return *(const int4*)(xlh + (size_t)s * 128 + c0);
    };
    auto process = [&](int4 xh, float w, bool valid) {
        float2 x01 = cvt_h2(xh.x), x23 = cvt_h2(xh.y);
        float2 x45 = cvt_h2(xh.z), x67 = cvt_h2(xh.w);
        float xs[8] = {x01.x, x01.y, x23.x, x23.y, x45.x, x45.y, x67.x, x67.y};
        float p = 0.f;
#pragma unroll
        for (int c = 0; c < 8; c++) {
            float z = xs[c] + fmaf(w, we[c], xv[c]);
            p = fmaf(at6[c], z, fmaf(at4[c], fabsf(z), p));  // leaky folded
        }
        p = dpp_sum_step<0xB1>(p);    // quad_perm [1,0,3,2]
        p = dpp_sum_step<0x4E>(p);    // quad_perm [2,3,0,1]  -> per-head sum
        float qe = valid ? __builtin_amdgcn_exp2f(p) : 0.f;
        l0 += qe;
#pragma unroll
        for (int c = 0; c < 8; c++) acc[c] = fmaf(qe, xs[c], acc[c]);
    };

    // rolling pipeline: records 4 iters ahead, gathers 2 ahead
    int2 r0 = recload(0), r1 = recload(1), r2 = recload(2), r3 = recload(3);
    int4 x0 = gatherx(r0.x), x1 = gatherx(r1.x);
    for (int i = 0; i < T; ++i) {
        int2 r4 = recload(i + 4);
        int4 x2 = gatherx(r2.x);
        process(x0, __int_as_float(r0.y), (e0 + (i << 2) + g) < e1);
        r0 = r1; r1 = r2; r2 = r3; r3 = r4;
        x0 = x1; x1 = x2;
    }

    // combine the 4 edge groups
    l0 += __shfl_xor(l0, 16, 64);
    l0 += __shfl_xor(l0, 32, 64);
#pragma unroll
    for (int c = 0; c < 8; c++) {
        acc[c] += __shfl_xor(acc[c], 16, 64);
        acc[c] += __shfl_xor(acc[c], 32, 64);
    }
    float rdenom = 1.0f / (l0 + 1e-16f);
    float r[8];
#pragma unroll
    for (int c = 0; c < 8; c++) r[c] = acc[c] * rdenom;

    if (mode == 0) {
        if (g == 0) {
            float4 bA = *(const float4*)(bias + c0);
            float4 bB = *(const float4*)(bias + c0 + 4);
            float bv[8] = {bA.x, bA.y, bA.z, bA.w, bB.x, bB.y, bB.z, bB.w};
            float o[8];
#pragma unroll
            for (int c = 0; c < 8; c++) {
                float v = r[c] + bv[c];
                o[c] = (v > 0.f) ? v : (__expf(v) - 1.f);   // ELU
            }
            __half2 p0 = __floats2half2_rn(o[0], o[1]);
            __half2 p1 = __floats2half2_rn(o[2], o[3]);
            __half2 p2 = __floats2half2_rn(o[4], o[5]);
            __half2 p3 = __floats2half2_rn(o[6], o[7]);
            int4 pk = make_int4(*(int*)&p0, *(int*)&p1, *(int*)&p2, *(int*)&p3);
            *(int4*)((__half*)out + (size_t)n * 128 + c0) = pk;
        }
    } else {
#pragma unroll
        for (int c = 0; c < 8; c++) {
            r[c] += __shfl_xor(r[c], 4, 64);
            r[c] += __shfl_xor(r[c], 8, 64);
        }
        if (lane < 4) {
            int w0 = lane << 3;
            float4 bA = *(const float4*)(bias + w0);
            float4 bB = *(const float4*)(bias + w0 + 4);
            float bv[8] = {bA.x, bA.y, bA.z, bA.w, bB.x, bB.y, bB.z, bB.w};
            float o[8];
#pragma unroll
            for (int c = 0; c < 8; c++) o[c] = 0.25f * r[c] + bv[c];
            float* op = (float*)out + (size_t)n * 32 + w0;
            *(float4*)op       = make_float4(o[0], o[1], o[2], o[3]);
            *(float4*)(op + 4) = make_float4(o[4], o[5], o[6], o[7]);
        }
    }
}

extern "C" void kernel_launch(void* const* d_in, const int* in_sizes, int n_in,
                              void* d_out, int out_size, void* d_ws, size_t ws_size,
                              hipStream_t stream) {
    const float* x    = (const float*)d_in[0];
    const int*  eidx  = (const int*)d_in[1];
    const float* ew   = (const float*)d_in[2];
    const float* Wl1  = (const float*)d_in[3];
    const float* Wr1  = (const float*)d_in[4];
    const float* We1  = (const float*)d_in[5];
    const float* att1 = (const float*)d_in[6];
    const float* b1   = (const float*)d_in[7];
    const float* Wl2  = (const float*)d_in[8];
    const float* Wr2  = (const float*)d_in[9];
    const float* We2  = (const float*)d_in[10];
    const float* att2 = (const float*)d_in[11];
    const float* b2   = (const float*)d_in[12];

    const int N = in_sizes[0] / 128;
    const int E = in_sizes[1] / 2;
    const int* src = eidx;
    const int* dst = eidx + E;
    const int NBK = (N + 255) >> 8;

    char* p = (char*)d_ws;
    auto alloc = [&](size_t bytes) -> void* {
        void* r = (void*)p;
        p += (bytes + 255) & ~(size_t)255;
        return r;
    };
    __half* xlh   = (__half*)alloc((size_t)N * 128 * sizeof(__half));
    float* xr     = (float*)alloc((size_t)N * 128 * sizeof(float));
    __half* h1h   = (__half*)alloc((size_t)N * 128 * sizeof(float));  // fp16 used; fp32-sized (srec alias)
    int2*  crec   = (int2*)alloc((size_t)(E + N + 64) * sizeof(int2));
    int*   rowp   = (int*)alloc((size_t)(N + 1) * sizeof(int));
    int*   cnt    = (int*)alloc((size_t)N * sizeof(int));
    int*   bcnt   = (int*)alloc(260 * sizeof(int));
    float* sumbuf = (float*)(bcnt + 256);
    int*   bbase  = (int*)alloc(260 * sizeof(int));
    int*   bcur   = (int*)alloc(260 * sizeof(int));
    int*   bsum   = (int*)alloc(256 * sizeof(int));
    _Float16* Wh1 = (_Float16*)alloc(32768 * sizeof(_Float16));
    _Float16* Wh2 = (_Float16*)alloc(32768 * sizeof(_Float16));
    int2*  srec   = (int2*)h1h;                     // staging aliased into h1

    // weight pre-pack (both layers) + zeroing of bcnt/sumbuf/bcur
    prep_w2_kernel<<<256, 256, 0, stream>>>(Wl1, Wr1, Wl2, Wr2, Wh1, Wh2,
                                            bcnt, bcur);

    bucket_hist_sum<<<1024, 256, 0, stream>>>(dst, ew, bcnt, sumbuf, E);
    partition_kernel<<<(E + 2047) / 2048, 256, 0, stream>>>(
        src, dst, ew, bcnt, bcur, bbase, srec, E, NBK);
    dst_hist_kernel<<<NBK, 1024, 0, stream>>>(srec, bbase, cnt, N);

    int nb = (N + 255) / 256;
    scan1_kernel<<<nb, 256, 0, stream>>>(cnt, rowp, bsum, N);
    scan3_kernel<<<nb, 256, 0, stream>>>(rowp, bsum, cnt, sumbuf, crec, N, E, nb);

    refine_kernel<<<NBK, 1024, 0, stream>>>(srec, bbase, rowp, crec, N);

    // Layer 1 (fp32 input)
    gemm_mfma_kernel<float><<<(N + 63) / 64, 256, 0, stream>>>(x, Wh1, xlh, xr, N);
    agg_kernel<<<(N + 3) / 4, 256, 0, stream>>>(xlh, xr, rowp, crec,
                                                We1, att1, b1, (void*)h1h, N, 0);
    // Layer 2 (fp16 input)
    gemm_mfma_kernel<_Float16><<<(N + 63) / 64, 256, 0, stream>>>(
        (const _Float16*)h1h, Wh2, xlh, xr, N);
    agg_kernel<<<(N + 3) / 4, 256, 0, stream>>>(xlh, xr, rowp, crec,
                                                We2, att2, b2, d_out, N, 1);
}

// Round 15
// 354.047 us; speedup vs baseline: 1.1915x; 1.0256x over previous
//
#include <hip/hip_runtime.h>
#include <hip/hip_fp16.h>
#include <math.h>
#include <type_traits>

// ---------------------------------------------------------------------------
// GATv2 x2 layers.
//   - CSR-by-dst via two-level counting sort (r7: direct scatter = 8x HBM
//     write amplification; bucket sort buys L2 write locality. r13: degree
//     counting must be LDS-histogram, never global atomics).
//   - r15: dst_hist + scan1 + scan3 + refine fused into ONE per-bucket
//     build_csr kernel. Key identity: every node has exactly one self-loop,
//     so rowp[first node of bucket b] = bbase[b] + 256*b (closed form) and
//     the row-pointer scan is block-local. 11 -> 8 launches, -2 passes.
//   - GEMMs on the MATRIX pipe: fp16 MFMA 16x16x32, fp32 accumulate.
//     r11 shape (4 waves x 4 col-tiles; r12: lower-VGPR variant worse).
//     Templated input: layer1 fp32, layer2 fp16 h1 (bit-identical, -25.6MB).
//   - Aggregation: EXACT round-1 form (proven 68.5us @ 89% VALUBusy):
//     one wave per node, 4 edges/iter, records 4 ahead / gathers 2 ahead,
//     dynamic loop, cvt_h2+fmaf body (r2-r5: asm/unroll degrade scheduling).
// ---------------------------------------------------------------------------

typedef _Float16 half8 __attribute__((ext_vector_type(8)));
typedef float floatx4 __attribute__((ext_vector_type(4)));

__global__ __launch_bounds__(256) void bucket_hist_sum(
    const int* __restrict__ dst, const float* __restrict__ ew,
    int* __restrict__ bcnt, float* __restrict__ sumbuf, int E) {
    __shared__ int h[256];
    h[threadIdx.x] = 0;
    __syncthreads();
    float s = 0.f;
    for (int i = blockIdx.x * blockDim.x + threadIdx.x; i < E; i += gridDim.x * blockDim.x) {
        atomicAdd(&h[dst[i] >> 8], 1);
        s += ew[i];
    }
#pragma unroll
    for (int off = 1; off <= 32; off <<= 1)
        s += __shfl_xor(s, off, 64);
    if ((threadIdx.x & 63) == 0)
        atomicAdd(sumbuf, s);
    __syncthreads();
    int v = h[threadIdx.x];
    if (v) atomicAdd(&bcnt[threadIdx.x], v);
}

// Partition edges into 256-node buckets. Absorbs bucket_scan (each block
// redundantly scans bcnt in LDS; bcur is a ZERO-based relative cursor).
// Block 0 publishes bbase for build_csr (read by later launches only).
__global__ __launch_bounds__(256) void partition_kernel(
    const int* __restrict__ src, const int* __restrict__ dst, const float* __restrict__ ew,
    const int* __restrict__ bcnt, int* __restrict__ bcur, int* __restrict__ bbase,
    int2* __restrict__ srec, int E, int NBK) {
    __shared__ int ex[256];
    __shared__ int h[256];
    __shared__ int gb[256];
    const int t = threadIdx.x;

    // redundant exclusive scan of bcnt (replaces bucket_scan kernel)
    int v = (t < NBK) ? bcnt[t] : 0;
    ex[t] = v;
    __syncthreads();
    for (int off = 1; off < 256; off <<= 1) {
        int y = 0;
        if (t >= off) y = ex[t - off];
        __syncthreads();
        ex[t] += y;
        __syncthreads();
    }
    const int exbase = ex[t] - v;              // exclusive scan value for bucket t
    if (blockIdx.x == 0 && t <= NBK) bbase[t] = exbase;

    h[t] = 0;
    __syncthreads();
    const int base = blockIdx.x * 2048;
    int d[8], sv[8];
    float wv[8];
#pragma unroll
    for (int j = 0; j < 8; j++) {
        int i = base + t + j * 256;
        if (i < E) {
            d[j] = dst[i];
            sv[j] = src[i];
            wv[j] = ew[i];
            atomicAdd(&h[d[j] >> 8], 1);
        } else {
            d[j] = -1;
        }
    }
    __syncthreads();
    int cntt = h[t];
    if (cntt) gb[t] = exbase + atomicAdd(&bcur[t], cntt);
    h[t] = 0;
    __syncthreads();
#pragma unroll
    for (int j = 0; j < 8; j++) {
        if (d[j] >= 0) {
            int b = d[j] >> 8;
            int r = atomicAdd(&h[b], 1);
            int pos = gb[b] + r;
            // pack src (bits 0..19) | (dst&255) << 20
            srec[pos] = make_int2(sv[j] | ((d[j] & 255) << 20), __float_as_int(wv[j]));
        }
    }
}

// Fused dst_hist + scan1 + scan3 + refine (r15). Per bucket b:
//   1. LDS histogram of the bucket's records (4-way privatized).
//   2. Block-local scan of (deg+1); global base is CLOSED-FORM:
//      bbase[b] + 256*b (every node contributes exactly 1 self-loop).
//   3. Write rowp, self-loop record, init LDS cursors.
//   4. Scatter the bucket's edges into crec (srec slab is L2-hot from 1).
// All block-local -- no cross-block sync (r9 crash class excluded).
__global__ __launch_bounds__(1024) void build_csr_kernel(
    const int2* __restrict__ srec, const int* __restrict__ bbase,
    const float* __restrict__ sumbuf, int* __restrict__ rowp,
    int2* __restrict__ crec, int N, int E) {
    __shared__ int h4[4][256];
    __shared__ int sc[256];
    __shared__ int cur[256];
    const int t = threadIdx.x;            // 0..1023
    const int grp = t >> 8, sub = t & 255;
    h4[grp][sub] = 0;
    __syncthreads();
    const int b = blockIdx.x;
    const int e0 = bbase[b], e1 = bbase[b + 1];
    for (int i = e0 + t; i < e1; i += 1024)
        atomicAdd(&h4[grp][(srec[i].x >> 20) & 255], 1);
    __syncthreads();
    int deg = 0;
    if (t < 256) {
        deg = h4[0][t] + h4[1][t] + h4[2][t] + h4[3][t];
        int node = (b << 8) + t;
        sc[t] = (node < N) ? (deg + 1) : 0;
    }
    __syncthreads();
    for (int off = 1; off < 256; off <<= 1) {     // inclusive scan (256 lanes)
        int y = 0;
        if (t < 256 && t >= off) y = sc[t - off];
        __syncthreads();
        if (t < 256) sc[t] += y;
        __syncthreads();
    }
    const int base = bbase[b] + (b << 8);
    if (t < 256) {
        int node = (b << 8) + t;
        if (node < N) {
            int rp = base + sc[t] - (deg + 1);    // exclusive position
            rowp[node] = rp;
            cur[t] = rp;
            crec[rp + deg] = make_int2(node, __float_as_int(sumbuf[0] * (1.0f / (float)E)));
            if (node == N - 1) rowp[N] = E + N;
        }
    }
    __syncthreads();
    for (int i = e0 + t; i < e1; i += 1024) {
        int2 rec = srec[i];
        int dlow = (rec.x >> 20) & 255;
        int pos = atomicAdd(&cur[dlow], 1);
        crec[pos] = make_int2(rec.x & 0xFFFFF, rec.y);
    }
}

// ---------------------------------------------------------------------------
// Pre-pack BOTH layers' W = [Wa | Wb] into fragment-ordered fp16 (one launch)
// and zero bcnt[0..259] + bcur[0..259].
// ---------------------------------------------------------------------------
__global__ __launch_bounds__(256) void prep_w2_kernel(
    const float* __restrict__ Wa1, const float* __restrict__ Wb1,
    const float* __restrict__ Wa2, const float* __restrict__ Wb2,
    _Float16* __restrict__ Wh1, _Float16* __restrict__ Wh2,
    int* __restrict__ bcnt, int* __restrict__ bcur) {
    const int bid = blockIdx.x;                 // 0..255
    if (bid == 0 && threadIdx.x < 260) bcnt[threadIdx.x] = 0;
    if (bid == 1 && threadIdx.x < 260) bcur[threadIdx.x] = 0;
    const int sel = bid >> 7;
    const float* Wa = sel ? Wa2 : Wa1;
    const float* Wb = sel ? Wb2 : Wb1;
    _Float16* Wh = sel ? Wh2 : Wh1;
    int tid = (bid & 127) * 256 + threadIdx.x;  // 0 .. 32767
    int j = tid & 7;
    int lane = (tid >> 3) & 63;
    int f = tid >> 9;                           // 0..63
    int kk = f & 3;
    int ct = f >> 2;                            // 0..15
    int col = ct * 16 + (lane & 15);
    int k = kk * 32 + ((lane >> 4) << 3) + j;
    float v = (col < 128) ? Wa[k * 128 + col] : Wb[k * 128 + (col - 128)];
    Wh[tid] = (_Float16)v;
}

// ---------------------------------------------------------------------------
// Dual GEMM on the matrix pipe: Yh = half(X@Wa) [Nx128], Yb = X@Wb [Nx128].
// Templated input T: fp32 (layer 1, converted during staging) or fp16
// (layer 2, straight copy -- numerically identical, half the traffic).
// Block: 64 rows x 256 cols, 4 waves x 4 col-tiles (r11 shape; r12 showed
// 8x2 lower-VGPR variant is slightly worse). Swapped operands (D = W^T X^T);
// r6 epilogue (r8 lesson: LDS-transpose store-coalescing is a net loss).
// ---------------------------------------------------------------------------
template <typename T>
__global__ __launch_bounds__(256) void gemm_mfma_kernel(
    const T* __restrict__ X, const _Float16* __restrict__ Wh,
    __half* __restrict__ Yh, float* __restrict__ Yb, int N) {
    __shared__ _Float16 Xs[64 * 128];            // 16 KB, swizzled
    const int tid = threadIdx.x;
    const int lane = tid & 63;
    const int w = tid >> 6;
    const int rb = blockIdx.x * 64;

    // W fragments -> registers (16 x coalesced 16B/lane loads)
    half8 wf[4][4];
#pragma unroll
    for (int ct = 0; ct < 4; ct++)
#pragma unroll
        for (int kk = 0; kk < 4; kk++)
            wf[ct][kk] = *(const half8*)(Wh + (size_t)(((w * 4 + ct) * 4 + kk) * 512 + lane * 8));

    // Stage X tile into swizzled LDS.
    if constexpr (std::is_same<T, float>::value) {
        // fp32 -> fp16 convert; 2048 float4-chunks / 256 threads.
#pragma unroll
        for (int it = 0; it < 8; it++) {
            int c = it * 256 + tid;
            int row = c >> 5;
            int f4 = c & 31;
            float4 v = make_float4(0.f, 0.f, 0.f, 0.f);
            if (rb + row < N)
                v = ((const float4*)X)[(size_t)(rb + row) * 32 + f4];
            _Float16 h[4] = {(_Float16)v.x, (_Float16)v.y, (_Float16)v.z, (_Float16)v.w};
            int byteoff = row * 256 + ((f4 * 8) ^ ((row & 7) << 4));
            *(uint2*)((char*)Xs + byteoff) = *(uint2*)h;
        }
    } else {
        // fp16 straight copy; 1024 int4-chunks / 256 threads.
#pragma unroll
        for (int it = 0; it < 4; it++) {
            int c = it * 256 + tid;
            int row = c >> 4;
            int f16 = c & 15;
            int4 v = make_int4(0, 0, 0, 0);
            if (rb + row < N)
                v = ((const int4*)X)[(size_t)(rb + row) * 16 + f16];
            int byteoff = row * 256 + ((f16 * 16) ^ ((row & 7) << 4));
            *(int4*)((char*)Xs + byteoff) = v;
        }
    }
    __syncthreads();

    floatx4 acc[4][4];
#pragma unroll
    for (int ct = 0; ct < 4; ct++)
#pragma unroll
        for (int rt = 0; rt < 4; rt++)
            acc[ct][rt] = (floatx4){0.f, 0.f, 0.f, 0.f};

#pragma unroll
    for (int kk = 0; kk < 4; kk++) {
        half8 xf[4];
#pragma unroll
        for (int rt = 0; rt < 4; rt++) {
            int row = rt * 16 + (lane & 15);
            int kb = kk * 64 + ((lane >> 4) << 4);
            int off = row * 256 + (kb ^ ((row & 7) << 4));
            xf[rt] = *(const half8*)((const char*)Xs + off);
        }
#pragma unroll
        for (int ct = 0; ct < 4; ct++)
#pragma unroll
            for (int rt = 0; rt < 4; rt++)
                acc[ct][rt] = __builtin_amdgcn_mfma_f32_16x16x32_f16(
                    wf[ct][kk], xf[rt], acc[ct][rt], 0, 0, 0);
    }

    // Epilogue: lane owns row rb+rt*16+(lane&15), cols gct*16+(lane>>4)*4 ..+3
    const int rsub = lane & 15;
    const int c4 = (lane >> 4) << 2;
#pragma unroll
    for (int ct = 0; ct < 4; ct++) {
        int gct = w * 4 + ct;
#pragma unroll
        for (int rt = 0; rt < 4; rt++) {
            int row = rb + rt * 16 + rsub;
            if (row < N) {
                floatx4 a = acc[ct][rt];
                if (gct < 8) {
                    int col = gct * 16 + c4;
                    __half2 hp[2];
                    hp[0] = __floats2half2_rn(a[0], a[1]);
                    hp[1] = __floats2half2_rn(a[2], a[3]);
                    *(uint2*)(Yh + (size_t)row * 128 + col) = *(uint2*)hp;
                } else {
                    int col = (gct - 8) * 16 + c4;
                    *(float4*)(Yb + (size_t)row * 128 + col) =
                        make_float4(a[0], a[1], a[2], a[3]);
                }
            }
        }
    }
}

// DPP partial-sum step within quads on the VALU pipe.
template <int CTRL>
__device__ __forceinline__ float dpp_sum_step(float v) {
    int t = __builtin_amdgcn_update_dpp(0, __float_as_int(v), CTRL, 0xF, 0xF, true);
    return v + __int_as_float(t);
}

__device__ __forceinline__ float2 cvt_h2(unsigned u) {
    __half2 h = *(__half2*)&u;
    return __half22float2(h);
}

// One wave per node; 4 edges/iteration.
// lane l: g=l>>4 (edge slot), q=l&15 -> channels 8q..8q+7 (head q>>2).
// Pipeline: records 4 iters ahead, gathers 2 iters ahead.  (round-1 exact)
// mode 0: ELU output stored as fp16 (h1), packed via __half2 pairs;
// mode 1: fp32 final output.
__global__ __launch_bounds__(256) void agg_kernel(
    const __half* __restrict__ xlh, const float* __restrict__ xr,
    const int* __restrict__ rowp, const int2* __restrict__ crec,
    const float* __restrict__ We, const float* __restrict__ att, const float* __restrict__ bias,
    void* __restrict__ out, int N, int mode) {
    const int wid = threadIdx.x >> 6;
    const int lane = threadIdx.x & 63;
    const int n = blockIdx.x * 4 + wid;
    if (n >= N) return;
    const int g = lane >> 4;
    const int q = lane & 15;
    const int c0 = q << 3;                         // channel base, 8 per lane
    const float LOG2E = 1.4426950408889634f;

    float we[8], xv[8], at6[8], at4[8];
    {
        float4 wA = *(const float4*)(We + c0);
        float4 wB = *(const float4*)(We + c0 + 4);
        we[0]=wA.x; we[1]=wA.y; we[2]=wA.z; we[3]=wA.w;
        we[4]=wB.x; we[5]=wB.y; we[6]=wB.z; we[7]=wB.w;
        float4 rA = *(const float4*)(xr + (size_t)n * 128 + c0);
        float4 rB = *(const float4*)(xr + (size_t)n * 128 + c0 + 4);
        xv[0]=rA.x; xv[1]=rA.y; xv[2]=rA.z; xv[3]=rA.w;
        xv[4]=rB.x; xv[5]=rB.y; xv[6]=rB.z; xv[7]=rB.w;
        float4 aA = *(const float4*)(att + c0);
        float4 aB = *(const float4*)(att + c0 + 4);
        float av[8] = {aA.x, aA.y, aA.z, aA.w, aB.x, aB.y, aB.z, aB.w};
#pragma unroll
        for (int c = 0; c < 8; c++) {
            at6[c] = 0.6f * LOG2E * av[c];
            at4[c] = 0.4f * LOG2E * av[c];
        }
    }

    float acc[8];
#pragma unroll
    for (int c = 0; c < 8; c++) acc[c] = 0.f;
    float l0 = 0.f;

    const int e0 = __builtin_amdgcn_readfirstlane(rowp[n]);
    const int e1 = __builtin_amdgcn_readfirstlane(rowp[n + 1]);
    const int cnt = e1 - e0;
    const int T = (cnt + 3) >> 2;

    auto recload = [&](int i) -> int2 {
        int idx = e0 + (i << 2) + g;
        idx = (idx < e1 - 1) ? idx : (e1 - 1);     // clamp (always valid)
        return crec[idx];
    };
    auto gatherx = [&](int s) -> int4 {            // 8 halves = 16B
        return *(const int4*)(xlh + (size_t)s * 128 + c0);
    };
    auto process = [&](int4 xh, float w, bool valid) {
        float2 x01 = cvt_h2(xh.x), x23 = cvt_h2(xh.y);
        float2 x45 = cvt_h2(xh.z), x67 = cvt_h2(xh.w);
        float xs[8] = {x01.x, x01.y, x23.x, x23.y, x45.x, x45.y, x67.x, x67.y};
        float p = 0.f;
#pragma unroll
        for (int c = 0; c < 8; c++) {
            float z = xs[c] + fmaf(w, we[c], xv[c]);
            p = fmaf(at6[c], z, fmaf(at4[c], fabsf(z), p));  // leaky folded
        }
        p = dpp_sum_step<0xB1>(p);    // quad_perm [1,0,3,2]
        p = dpp_sum_step<0x4E>(p);    // quad_perm [2,3,0,1]  -> per-head sum
        float qe = valid ? __builtin_amdgcn_exp2f(p) : 0.f;
        l0 += qe;
#pragma unroll
        for (int c = 0; c < 8; c++) acc[c] = fmaf(qe, xs[c], acc[c]);
    };

    // rolling pipeline: records 4 iters ahead, gathers 2 ahead
    int2 r0 = recload(0), r1 = recload(1), r2 = recload(2), r3 = recload(3);
    int4 x0 = gatherx(r0.x), x1 = gatherx(r1.x);
    for (int i = 0; i < T; ++i) {
        int2 r4 = recload(i + 4);
        int4 x2 = gatherx(r2.x);
        process(x0, __int_as_float(r0.y), (e0 + (i << 2) + g) < e1);
        r0 = r1; r1 = r2; r2 = r3; r3 = r4;
        x0 = x1; x1 = x2;
    }

    // combine the 4 edge groups
    l0 += __shfl_xor(l0, 16, 64);
    l0 += __shfl_xor(l0, 32, 64);
#pragma unroll
    for (int c = 0; c < 8; c++) {
        acc[c] += __shfl_xor(acc[c], 16, 64);
        acc[c] += __shfl_xor(acc[c], 32, 64);
    }
    float rdenom = 1.0f / (l0 + 1e-16f);
    float r[8];
#pragma unroll
    for (int c = 0; c < 8; c++) r[c] = acc[c] * rdenom;

    if (mode == 0) {
        if (g == 0) {
            float4 bA = *(const float4*)(bias + c0);
            float4 bB = *(const float4*)(bias + c0 + 4);
            float bv[8] = {bA.x, bA.y, bA.z, bA.w, bB.x, bB.y, bB.z, bB.w};
            float o[8];
#pragma unroll
            for (int c = 0; c < 8; c++) {
                float v = r[c] + bv[c];
                o[c] = (v > 0.f) ? v : (__expf(v) - 1.f);   // ELU
            }
            __half2 p0 = __floats2half2_rn(o[0], o[1]);
            __half2 p1 = __floats2half2_rn(o[2], o[3]);
            __half2 p2 = __floats2half2_rn(o[4], o[5]);
            __half2 p3 = __floats2half2_rn(o[6], o[7]);
            int4 pk = make_int4(*(int*)&p0, *(int*)&p1, *(int*)&p2, *(int*)&p3);
            *(int4*)((__half*)out + (size_t)n * 128 + c0) = pk;
        }
    } else {
#pragma unroll
        for (int c = 0; c < 8; c++) {
            r[c] += __shfl_xor(r[c], 4, 64);
            r[c] += __shfl_xor(r[c], 8, 64);
        }
        if (lane < 4) {
            int w0 = lane << 3;
            float4 bA = *(const float4*)(bias + w0);
            float4 bB = *(const float4*)(bias + w0 + 4);
            float bv[8] = {bA.x, bA.y, bA.z, bA.w, bB.x, bB.y, bB.z, bB.w};
            float o[8];
#pragma unroll
            for (int c = 0; c < 8; c++) o[c] = 0.25f * r[c] + bv[c];
            float* op = (float*)out + (size_t)n * 32 + w0;
            *(float4*)op       = make_float4(o[0], o[1], o[2], o[3]);
            *(float4*)(op + 4) = make_float4(o[4], o[5], o[6], o[7]);
        }
    }
}

extern "C" void kernel_launch(void* const* d_in, const int* in_sizes, int n_in,
                              void* d_out, int out_size, void* d_ws, size_t ws_size,
                              hipStream_t stream) {
    const float* x    = (const float*)d_in[0];
    const int*  eidx  = (const int*)d_in[1];
    const float* ew   = (const float*)d_in[2];
    const float* Wl1  = (const float*)d_in[3];
    const float* Wr1  = (const float*)d_in[4];
    const float* We1  = (const float*)d_in[5];
    const float* att1 = (const float*)d_in[6];
    const float* b1   = (const float*)d_in[7];
    const float* Wl2  = (const float*)d_in[8];
    const float* Wr2  = (const float*)d_in[9];
    const float* We2  = (const float*)d_in[10];
    const float* att2 = (const float*)d_in[11];
    const float* b2   = (const float*)d_in[12];

    const int N = in_sizes[0] / 128;
    const int E = in_sizes[1] / 2;
    const int* src = eidx;
    const int* dst = eidx + E;
    const int NBK = (N + 255) >> 8;

    char* p = (char*)d_ws;
    auto alloc = [&](size_t bytes) -> void* {
        void* r = (void*)p;
        p += (bytes + 255) & ~(size_t)255;
        return r;
    };
    __half* xlh   = (__half*)alloc((size_t)N * 128 * sizeof(__half));
    float* xr     = (float*)alloc((size_t)N * 128 * sizeof(float));
    __half* h1h   = (__half*)alloc((size_t)N * 128 * sizeof(float));  // fp16 used; fp32-sized (srec alias)
    int2*  crec   = (int2*)alloc((size_t)(E + N + 64) * sizeof(int2));
    int*   rowp   = (int*)alloc((size_t)(N + 1) * sizeof(int));
    int*   bcnt   = (int*)alloc(260 * sizeof(int));
    float* sumbuf = (float*)(bcnt + 256);
    int*   bbase  = (int*)alloc(260 * sizeof(int));
    int*   bcur   = (int*)alloc(260 * sizeof(int));
    _Float16* Wh1 = (_Float16*)alloc(32768 * sizeof(_Float16));
    _Float16* Wh2 = (_Float16*)alloc(32768 * sizeof(_Float16));
    int2*  srec   = (int2*)h1h;                     // staging aliased into h1

    // weight pre-pack (both layers) + zeroing of bcnt/sumbuf/bcur
    prep_w2_kernel<<<256, 256, 0, stream>>>(Wl1, Wr1, Wl2, Wr2, Wh1, Wh2,
                                            bcnt, bcur);

    bucket_hist_sum<<<1024, 256, 0, stream>>>(dst, ew, bcnt, sumbuf, E);
    partition_kernel<<<(E + 2047) / 2048, 256, 0, stream>>>(
        src, dst, ew, bcnt, bcur, bbase, srec, E, NBK);
    build_csr_kernel<<<NBK, 1024, 0, stream>>>(srec, bbase, sumbuf, rowp,
                                               crec, N, E);

    // Layer 1 (fp32 input)
    gemm_mfma_kernel<float><<<(N + 63) / 64, 256, 0, stream>>>(x, Wh1, xlh, xr, N);
    agg_kernel<<<(N + 3) / 4, 256, 0, stream>>>(xlh, xr, rowp, crec,
                                                We1, att1, b1, (void*)h1h, N, 0);
    // Layer 2 (fp16 input)
    gemm_mfma_kernel<_Float16><<<(N + 63) / 64, 256, 0, stream>>>(
        (const _Float16*)h1h, Wh2, xlh, xr, N);
    agg_kernel<<<(N + 3) / 4, 256, 0, stream>>>(xlh, xr, rowp, crec,
                                                We2, att2, b2, d_out, N, 1);
}

// Round 16
// 344.432 us; speedup vs baseline: 1.2247x; 1.0279x over previous
//
#include <hip/hip_runtime.h>
#include <hip/hip_fp16.h>
#include <math.h>
#include <type_traits>

// ---------------------------------------------------------------------------
// GATv2 x2 layers.
//   - CSR-by-dst via two-level counting sort (r7: direct scatter = 8x HBM
//     write amplification; bucket sort buys L2 write locality. r13: degree
//     counting must be LDS-histogram, never global atomics).
//   - r15: dst_hist + scan1 + scan3 + refine fused into ONE per-bucket
//     build_csr kernel (closed-form row base: bbase[b] + 256*b).
//   - r16: partition at 1024 thr x 8 edges = 8192 edges/block (196 blocks).
//     r13 counters showed 5.3x srec write amplification at 2048/block
//     (~84B per bucket-window per block); 4x bigger chunks -> ~336B runs,
//     amplification ~1.2x.
//   - GEMMs on the MATRIX pipe: fp16 MFMA 16x16x32, fp32 accumulate.
//     r11 shape (4 waves x 4 col-tiles; r12: lower-VGPR variant worse).
//     Templated input: layer1 fp32, layer2 fp16 h1 (bit-identical, -25.6MB).
//   - Aggregation: EXACT round-1 form (proven 68.5us @ 89% VALUBusy):
//     one wave per node, 4 edges/iter, records 4 ahead / gathers 2 ahead,
//     dynamic loop, cvt_h2+fmaf body (r2-r5: asm/unroll degrade scheduling).
// ---------------------------------------------------------------------------

typedef _Float16 half8 __attribute__((ext_vector_type(8)));
typedef float floatx4 __attribute__((ext_vector_type(4)));

__global__ __launch_bounds__(256) void bucket_hist_sum(
    const int* __restrict__ dst, const float* __restrict__ ew,
    int* __restrict__ bcnt, float* __restrict__ sumbuf, int E) {
    __shared__ int h[256];
    h[threadIdx.x] = 0;
    __syncthreads();
    float s = 0.f;
    for (int i = blockIdx.x * blockDim.x + threadIdx.x; i < E; i += gridDim.x * blockDim.x) {
        atomicAdd(&h[dst[i] >> 8], 1);
        s += ew[i];
    }
#pragma unroll
    for (int off = 1; off <= 32; off <<= 1)
        s += __shfl_xor(s, off, 64);
    if ((threadIdx.x & 63) == 0)
        atomicAdd(sumbuf, s);
    __syncthreads();
    int v = h[threadIdx.x];
    if (v) atomicAdd(&bcnt[threadIdx.x], v);
}

// Partition edges into 256-node buckets. 1024 threads x 8 edges (r16:
// bigger per-block bucket chunks -> less srec write amplification).
// Absorbs bucket_scan (redundant LDS scan of bcnt; bcur is a ZERO-based
// relative cursor). Block 0 publishes bbase for build_csr.
__global__ __launch_bounds__(1024) void partition_kernel(
    const int* __restrict__ src, const int* __restrict__ dst, const float* __restrict__ ew,
    const int* __restrict__ bcnt, int* __restrict__ bcur, int* __restrict__ bbase,
    int2* __restrict__ srec, int E, int NBK) {
    __shared__ int ex[256];
    __shared__ int h[256];
    __shared__ int gb[256];
    const int t = threadIdx.x;                 // 0..1023

    // redundant exclusive scan of bcnt (replaces bucket_scan kernel)
    if (t < 256) ex[t] = (t < NBK) ? bcnt[t] : 0;
    __syncthreads();
    for (int off = 1; off < 256; off <<= 1) {
        int y = 0;
        if (t < 256 && t >= off) y = ex[t - off];
        __syncthreads();
        if (t < 256) ex[t] += y;
        __syncthreads();
    }
    if (blockIdx.x == 0 && t <= NBK)
        bbase[t] = (t < 256) ? (ex[t] - ((t < NBK) ? bcnt[t] : 0))
                             : ex[255];       // t == 256 (only if NBK == 256)
    if (t < 256) h[t] = 0;
    __syncthreads();

    const int base = blockIdx.x * 8192;
    int d[8], sv[8];
    float wv[8];
#pragma unroll
    for (int j = 0; j < 8; j++) {
        int i = base + t + j * 1024;
        if (i < E) {
            d[j] = dst[i];
            sv[j] = src[i];
            wv[j] = ew[i];
            atomicAdd(&h[d[j] >> 8], 1);
        } else {
            d[j] = -1;
        }
    }
    __syncthreads();
    if (t < 256) {
        int cntt = h[t];
        int exb = ex[t] - ((t < NBK) ? bcnt[t] : 0);
        if (cntt) gb[t] = exb + atomicAdd(&bcur[t], cntt);
        h[t] = 0;
    }
    __syncthreads();
#pragma unroll
    for (int j = 0; j < 8; j++) {
        if (d[j] >= 0) {
            int b = d[j] >> 8;
            int r = atomicAdd(&h[b], 1);
            int pos = gb[b] + r;
            // pack src (bits 0..19) | (dst&255) << 20
            srec[pos] = make_int2(sv[j] | ((d[j] & 255) << 20), __float_as_int(wv[j]));
        }
    }
}

// Fused dst_hist + scan1 + scan3 + refine (r15). Per bucket b:
//   1. LDS histogram of the bucket's records (4-way privatized).
//   2. Block-local scan of (deg+1); global base is CLOSED-FORM:
//      bbase[b] + 256*b (every node contributes exactly 1 self-loop).
//   3. Write rowp, self-loop record, init LDS cursors.
//   4. Scatter the bucket's edges into crec (srec slab is L2-hot from 1).
// All block-local -- no cross-block sync (r9 crash class excluded).
__global__ __launch_bounds__(1024) void build_csr_kernel(
    const int2* __restrict__ srec, const int* __restrict__ bbase,
    const float* __restrict__ sumbuf, int* __restrict__ rowp,
    int2* __restrict__ crec, int N, int E) {
    __shared__ int h4[4][256];
    __shared__ int sc[256];
    __shared__ int cur[256];
    const int t = threadIdx.x;            // 0..1023
    const int grp = t >> 8, sub = t & 255;
    h4[grp][sub] = 0;
    __syncthreads();
    const int b = blockIdx.x;
    const int e0 = bbase[b], e1 = bbase[b + 1];
    for (int i = e0 + t; i < e1; i += 1024)
        atomicAdd(&h4[grp][(srec[i].x >> 20) & 255], 1);
    __syncthreads();
    int deg = 0;
    if (t < 256) {
        deg = h4[0][t] + h4[1][t] + h4[2][t] + h4[3][t];
        int node = (b << 8) + t;
        sc[t] = (node < N) ? (deg + 1) : 0;
    }
    __syncthreads();
    for (int off = 1; off < 256; off <<= 1) {     // inclusive scan (256 lanes)
        int y = 0;
        if (t < 256 && t >= off) y = sc[t - off];
        __syncthreads();
        if (t < 256) sc[t] += y;
        __syncthreads();
    }
    const int base = bbase[b] + (b << 8);
    if (t < 256) {
        int node = (b << 8) + t;
        if (node < N) {
            int rp = base + sc[t] - (deg + 1);    // exclusive position
            rowp[node] = rp;
            cur[t] = rp;
            crec[rp + deg] = make_int2(node, __float_as_int(sumbuf[0] * (1.0f / (float)E)));
            if (node == N - 1) rowp[N] = E + N;
        }
    }
    __syncthreads();
    for (int i = e0 + t; i < e1; i += 1024) {
        int2 rec = srec[i];
        int dlow = (rec.x >> 20) & 255;
        int pos = atomicAdd(&cur[dlow], 1);
        crec[pos] = make_int2(rec.x & 0xFFFFF, rec.y);
    }
}

// ---------------------------------------------------------------------------
// Pre-pack BOTH layers' W = [Wa | Wb] into fragment-ordered fp16 (one launch)
// and zero bcnt[0..259] + bcur[0..259].
// ---------------------------------------------------------------------------
__global__ __launch_bounds__(256) void prep_w2_kernel(
    const float* __restrict__ Wa1, const float* __restrict__ Wb1,
    const float* __restrict__ Wa2, const float* __restrict__ Wb2,
    _Float16* __restrict__ Wh1, _Float16* __restrict__ Wh2,
    int* __restrict__ bcnt, int* __restrict__ bcur) {
    const int bid = blockIdx.x;                 // 0..255
    if (bid == 0 && threadIdx.x < 260) bcnt[threadIdx.x] = 0;
    if (bid == 1 && threadIdx.x < 260) bcur[threadIdx.x] = 0;
    const int sel = bid >> 7;
    const float* Wa = sel ? Wa2 : Wa1;
    const float* Wb = sel ? Wb2 : Wb1;
    _Float16* Wh = sel ? Wh2 : Wh1;
    int tid = (bid & 127) * 256 + threadIdx.x;  // 0 .. 32767
    int j = tid & 7;
    int lane = (tid >> 3) & 63;
    int f = tid >> 9;                           // 0..63
    int kk = f & 3;
    int ct = f >> 2;                            // 0..15
    int col = ct * 16 + (lane & 15);
    int k = kk * 32 + ((lane >> 4) << 3) + j;
    float v = (col < 128) ? Wa[k * 128 + col] : Wb[k * 128 + (col - 128)];
    Wh[tid] = (_Float16)v;
}

// ---------------------------------------------------------------------------
// Dual GEMM on the matrix pipe: Yh = half(X@Wa) [Nx128], Yb = X@Wb [Nx128].
// Templated input T: fp32 (layer 1, converted during staging) or fp16
// (layer 2, straight copy -- numerically identical, half the traffic).
// Block: 64 rows x 256 cols, 4 waves x 4 col-tiles (r11 shape; r12 showed
// 8x2 lower-VGPR variant is slightly worse). Swapped operands (D = W^T X^T);
// r6 epilogue (r8 lesson: LDS-transpose store-coalescing is a net loss).
// ---------------------------------------------------------------------------
template <typename T>
__global__ __launch_bounds__(256) void gemm_mfma_kernel(
    const T* __restrict__ X, const _Float16* __restrict__ Wh,
    __half* __restrict__ Yh, float* __restrict__ Yb, int N) {
    __shared__ _Float16 Xs[64 * 128];            // 16 KB, swizzled
    const int tid = threadIdx.x;
    const int lane = tid & 63;
    const int w = tid >> 6;
    const int rb = blockIdx.x * 64;

    // W fragments -> registers (16 x coalesced 16B/lane loads)
    half8 wf[4][4];
#pragma unroll
    for (int ct = 0; ct < 4; ct++)
#pragma unroll
        for (int kk = 0; kk < 4; kk++)
            wf[ct][kk] = *(const half8*)(Wh + (size_t)(((w * 4 + ct) * 4 + kk) * 512 + lane * 8));

    // Stage X tile into swizzled LDS.
    if constexpr (std::is_same<T, float>::value) {
        // fp32 -> fp16 convert; 2048 float4-chunks / 256 threads.
#pragma unroll
        for (int it = 0; it < 8; it++) {
            int c = it * 256 + tid;
            int row = c >> 5;
            int f4 = c & 31;
            float4 v = make_float4(0.f, 0.f, 0.f, 0.f);
            if (rb + row < N)
                v = ((const float4*)X)[(size_t)(rb + row) * 32 + f4];
            _Float16 h[4] = {(_Float16)v.x, (_Float16)v.y, (_Float16)v.z, (_Float16)v.w};
            int byteoff = row * 256 + ((f4 * 8) ^ ((row & 7) << 4));
            *(uint2*)((char*)Xs + byteoff) = *(uint2*)h;
        }
    } else {
        // fp16 straight copy; 1024 int4-chunks / 256 threads.
#pragma unroll
        for (int it = 0; it < 4; it++) {
            int c = it * 256 + tid;
            int row = c >> 4;
            int f16 = c & 15;
            int4 v = make_int4(0, 0, 0, 0);
            if (rb + row < N)
                v = ((const int4*)X)[(size_t)(rb + row) * 16 + f16];
            int byteoff = row * 256 + ((f16 * 16) ^ ((row & 7) << 4));
            *(int4*)((char*)Xs + byteoff) = v;
        }
    }
    __syncthreads();

    floatx4 acc[4][4];
#pragma unroll
    for (int ct = 0; ct < 4; ct++)
#pragma unroll
        for (int rt = 0; rt < 4; rt++)
            acc[ct][rt] = (floatx4){0.f, 0.f, 0.f, 0.f};

#pragma unroll
    for (int kk = 0; kk < 4; kk++) {
        half8 xf[4];
#pragma unroll
        for (int rt = 0; rt < 4; rt++) {
            int row = rt * 16 + (lane & 15);
            int kb = kk * 64 + ((lane >> 4) << 4);
            int off = row * 256 + (kb ^ ((row & 7) << 4));
            xf[rt] = *(const half8*)((const char*)Xs + off);
        }
#pragma unroll
        for (int ct = 0; ct < 4; ct++)
#pragma unroll
            for (int rt = 0; rt < 4; rt++)
                acc[ct][rt] = __builtin_amdgcn_mfma_f32_16x16x32_f16(
                    wf[ct][kk], xf[rt], acc[ct][rt], 0, 0, 0);
    }

    // Epilogue: lane owns row rb+rt*16+(lane&15), cols gct*16+(lane>>4)*4 ..+3
    const int rsub = lane & 15;
    const int c4 = (lane >> 4) << 2;
#pragma unroll
    for (int ct = 0; ct < 4; ct++) {
        int gct = w * 4 + ct;
#pragma unroll
        for (int rt = 0; rt < 4; rt++) {
            int row = rb + rt * 16 + rsub;
            if (row < N) {
                floatx4 a = acc[ct][rt];
                if (gct < 8) {
                    int col = gct * 16 + c4;
                    __half2 hp[2];
                    hp[0] = __floats2half2_rn(a[0], a[1]);
                    hp[1] = __floats2half2_rn(a[2], a[3]);
                    *(uint2*)(Yh + (size_t)row * 128 + col) = *(uint2*)hp;
                } else {
                    int col = (gct - 8) * 16 + c4;
                    *(float4*)(Yb + (size_t)row * 128 + col) =
                        make_float4(a[0], a[1], a[2], a[3]);
                }
            }
        }
    }
}

// DPP partial-sum step within quads on the VALU pipe.
template <int CTRL>
__device__ __forceinline__ float dpp_sum_step(float v) {
    int t = __builtin_amdgcn_update_dpp(0, __float_as_int(v), CTRL, 0xF, 0xF, true);
    return v + __int_as_float(t);
}

__device__ __forceinline__ float2 cvt_h2(unsigned u) {
    __half2 h = *(__half2*)&u;
    return __half22float2(h);
}

// One wave per node; 4 edges/iteration.
// lane l: g=l>>4 (edge slot), q=l&15 -> channels 8q..8q+7 (head q>>2).
// Pipeline: records 4 iters ahead, gathers 2 iters ahead.  (round-1 exact)
// mode 0: ELU output stored as fp16 (h1), packed via __half2 pairs;
// mode 1: fp32 final output.
__global__ __launch_bounds__(256) void agg_kernel(
    const __half* __restrict__ xlh, const float* __restrict__ xr,
    const int* __restrict__ rowp, const int2* __restrict__ crec,
    const float* __restrict__ We, const float* __restrict__ att, const float* __restrict__ bias,
    void* __restrict__ out, int N, int mode) {
    const int wid = threadIdx.x >> 6;
    const int lane = threadIdx.x & 63;
    const int n = blockIdx.x * 4 + wid;
    if (n >= N) return;
    const int g = lane >> 4;
    const int q = lane & 15;
    const int c0 = q << 3;                         // channel base, 8 per lane
    const float LOG2E = 1.4426950408889634f;

    float we[8], xv[8], at6[8], at4[8];
    {
        float4 wA = *(const float4*)(We + c0);
        float4 wB = *(const float4*)(We + c0 + 4);
        we[0]=wA.x; we[1]=wA.y; we[2]=wA.z; we[3]=wA.w;
        we[4]=wB.x; we[5]=wB.y; we[6]=wB.z; we[7]=wB.w;
        float4 rA = *(const float4*)(xr + (size_t)n * 128 + c0);
        float4 rB = *(const float4*)(xr + (size_t)n * 128 + c0 + 4);
        xv[0]=rA.x; xv[1]=rA.y; xv[2]=rA.z; xv[3]=rA.w;
        xv[4]=rB.x; xv[5]=rB.y; xv[6]=rB.z; xv[7]=rB.w;
        float4 aA = *(const float4*)(att + c0);
        float4 aB = *(const float4*)(att + c0 + 4);
        float av[8] = {aA.x, aA.y, aA.z, aA.w, aB.x, aB.y, aB.z, aB.w};
#pragma unroll
        for (int c = 0; c < 8; c++) {
            at6[c] = 0.6f * LOG2E * av[c];
            at4[c] = 0.4f * LOG2E * av[c];
        }
    }

    float acc[8];
#pragma unroll
    for (int c = 0; c < 8; c++) acc[c] = 0.f;
    float l0 = 0.f;

    const int e0 = __builtin_amdgcn_readfirstlane(rowp[n]);
    const int e1 = __builtin_amdgcn_readfirstlane(rowp[n + 1]);
    const int cnt = e1 - e0;
    const int T = (cnt + 3) >> 2;

    auto recload = [&](int i) -> int2 {
        int idx = e0 + (i << 2) + g;
        idx = (idx < e1 - 1) ? idx : (e1 - 1);     // clamp (always valid)
        return crec[idx];
    };
    auto gatherx = [&](int s) -> int4 {            // 8 halves = 16B
        return *(const int4*)(xlh + (size_t)s * 128 + c0);
    };
    auto process = [&](int4 xh, float w, bool valid) {
        float2 x01 = cvt_h2(xh.x), x23 = cvt_h2(xh.y);
        float2 x45 = cvt_h2(xh.z), x67 = cvt_h2(xh.w);
        float xs[8] = {x01.x, x01.y, x23.x, x23.y, x45.x, x45.y, x67.x, x67.y};
        float p = 0.f;
#pragma unroll
        for (int c = 0; c < 8; c++) {
            float z = xs[c] + fmaf(w, we[c], xv[c]);
            p = fmaf(at6[c], z, fmaf(at4[c], fabsf(z), p));  // leaky folded
        }
        p = dpp_sum_step<0xB1>(p);    // quad_perm [1,0,3,2]
        p = dpp_sum_step<0x4E>(p);    // quad_perm [2,3,0,1]  -> per-head sum
        float qe = valid ? __builtin_amdgcn_exp2f(p) : 0.f;
        l0 += qe;
#pragma unroll
        for (int c = 0; c < 8; c++) acc[c] = fmaf(qe, xs[c], acc[c]);
    };

    // rolling pipeline: records 4 iters ahead, gathers 2 ahead
    int2 r0 = recload(0), r1 = recload(1), r2 = recload(2), r3 = recload(3);
    int4 x0 = gatherx(r0.x), x1 = gatherx(r1.x);
    for (int i = 0; i < T; ++i) {
        int2 r4 = recload(i + 4);
        int4 x2 = gatherx(r2.x);
        process(x0, __int_as_float(r0.y), (e0 + (i << 2) + g) < e1);
        r0 = r1; r1 = r2; r2 = r3; r3 = r4;
        x0 = x1; x1 = x2;
    }

    // combine the 4 edge groups
    l0 += __shfl_xor(l0, 16, 64);
    l0 += __shfl_xor(l0, 32, 64);
#pragma unroll
    for (int c = 0; c < 8; c++) {
        acc[c] += __shfl_xor(acc[c], 16, 64);
        acc[c] += __shfl_xor(acc[c], 32, 64);
    }
    float rdenom = 1.0f / (l0 + 1e-16f);
    float r[8];
#pragma unroll
    for (int c = 0; c < 8; c++) r[c] = acc[c] * rdenom;

    if (mode == 0) {
        if (g == 0) {
            float4 bA = *(const float4*)(bias + c0);
            float4 bB = *(const float4*)(bias + c0 + 4);
            float bv[8] = {bA.x, bA.y, bA.z, bA.w, bB.x, bB.y, bB.z, bB.w};
            float o[8];
#pragma unroll
            for (int c = 0; c < 8; c++) {
                float v = r[c] + bv[c];
                o[c] = (v > 0.f) ? v : (__expf(v) - 1.f);   // ELU
            }
            __half2 p0 = __floats2half2_rn(o[0], o[1]);
            __half2 p1 = __floats2half2_rn(o[2], o[3]);
            __half2 p2 = __floats2half2_rn(o[4], o[5]);
            __half2 p3 = __floats2half2_rn(o[6], o[7]);
            int4 pk = make_int4(*(int*)&p0, *(int*)&p1, *(int*)&p2, *(int*)&p3);
            *(int4*)((__half*)out + (size_t)n * 128 + c0) = pk;
        }
    } else {
#pragma unroll
        for (int c = 0; c < 8; c++) {
            r[c] += __shfl_xor(r[c], 4, 64);
            r[c] += __shfl_xor(r[c], 8, 64);
        }
        if (lane < 4) {
            int w0 = lane << 3;
            float4 bA = *(const float4*)(bias + w0);
            float4 bB = *(const float4*)(bias + w0 + 4);
            float bv[8] = {bA.x, bA.y, bA.z, bA.w, bB.x, bB.y, bB.z, bB.w};
            float o[8];
#pragma unroll
            for (int c = 0; c < 8; c++) o[c] = 0.25f * r[c] + bv[c];
            float* op = (float*)out + (size_t)n * 32 + w0;
            *(float4*)op       = make_float4(o[0], o[1], o[2], o[3]);
            *(float4*)(op + 4) = make_float4(o[4], o[5], o[6], o[7]);
        }
    }
}

extern "C" void kernel_launch(void* const* d_in, const int* in_sizes, int n_in,
                              void* d_out, int out_size, void* d_ws, size_t ws_size,
                              hipStream_t stream) {
    const float* x    = (const float*)d_in[0];
    const int*  eidx  = (const int*)d_in[1];
    const float* ew   = (const float*)d_in[2];
    const float* Wl1  = (const float*)d_in[3];
    const float* Wr1  = (const float*)d_in[4];
    const float* We1  = (const float*)d_in[5];
    const float* att1 = (const float*)d_in[6];
    const float* b1   = (const float*)d_in[7];
    const float* Wl2  = (const float*)d_in[8];
    const float* Wr2  = (const float*)d_in[9];
    const float* We2  = (const float*)d_in[10];
    const float* att2 = (const float*)d_in[11];
    const float* b2   = (const float*)d_in[12];

    const int N = in_sizes[0] / 128;
    const int E = in_sizes[1] / 2;
    const int* src = eidx;
    const int* dst = eidx + E;
    const int NBK = (N + 255) >> 8;

    char* p = (char*)d_ws;
    auto alloc = [&](size_t bytes) -> void* {
        void* r = (void*)p;
        p += (bytes + 255) & ~(size_t)255;
        return r;
    };
    __half* xlh   = (__half*)alloc((size_t)N * 128 * sizeof(__half));
    float* xr     = (float*)alloc((size_t)N * 128 * sizeof(float));
    __half* h1h   = (__half*)alloc((size_t)N * 128 * sizeof(float));  // fp16 used; fp32-sized (srec alias)
    int2*  crec   = (int2*)alloc((size_t)(E + N + 64) * sizeof(int2));
    int*   rowp   = (int*)alloc((size_t)(N + 1) * sizeof(int));
    int*   bcnt   = (int*)alloc(260 * sizeof(int));
    float* sumbuf = (float*)(bcnt + 256);
    int*   bbase  = (int*)alloc(260 * sizeof(int));
    int*   bcur   = (int*)alloc(260 * sizeof(int));
    _Float16* Wh1 = (_Float16*)alloc(32768 * sizeof(_Float16));
    _Float16* Wh2 = (_Float16*)alloc(32768 * sizeof(_Float16));
    int2*  srec   = (int2*)h1h;                     // staging aliased into h1

    // weight pre-pack (both layers) + zeroing of bcnt/sumbuf/bcur
    prep_w2_kernel<<<256, 256, 0, stream>>>(Wl1, Wr1, Wl2, Wr2, Wh1, Wh2,
                                            bcnt, bcur);

    bucket_hist_sum<<<1024, 256, 0, stream>>>(dst, ew, bcnt, sumbuf, E);
    partition_kernel<<<(E + 8191) / 8192, 1024, 0, stream>>>(
        src, dst, ew, bcnt, bcur, bbase, srec, E, NBK);
    build_csr_kernel<<<NBK, 1024, 0, stream>>>(srec, bbase, sumbuf, rowp,
                                               crec, N, E);

    // Layer 1 (fp32 input)
    gemm_mfma_kernel<float><<<(N + 63) / 64, 256, 0, stream>>>(x, Wh1, xlh, xr, N);
    agg_kernel<<<(N + 3) / 4, 256, 0, stream>>>(xlh, xr, rowp, crec,
                                                We1, att1, b1, (void*)h1h, N, 0);
    // Layer 2 (fp16 input)
    gemm_mfma_kernel<_Float16><<<(N + 63) / 64, 256, 0, stream>>>(
        (const _Float16*)h1h, Wh2, xlh, xr, N);
    agg_kernel<<<(N + 3) / 4, 256, 0, stream>>>(xlh, xr, rowp, crec,
                                                We2, att2, b2, d_out, N, 1);
}

// Round 17
// 338.442 us; speedup vs baseline: 1.2464x; 1.0177x over previous
//
#include <hip/hip_runtime.h>
#include <hip/hip_fp16.h>
#include <math.h>
#include <type_traits>

// ---------------------------------------------------------------------------
// GATv2 x2 layers.
//   - CSR-by-dst via two-level counting sort (r7: direct scatter = 8x HBM
//     write amplification; bucket sort buys L2 write locality. r13: degree
//     counting must be LDS-histogram, never global atomics).
//   - r15: build_csr fuses dst_hist+scan1+scan3+refine (closed-form row
//     base bbase[b]+256*b). r16: partition at 8192 edges/block (write-amp).
//   - r17: gemm is MULTI-TILE with register prefetch (T14 async-STAGE):
//     grid = ceil(NT/2), each block strides over 2 tiles; W fragments load
//     once per block; next tile's X loads issue right after ds_write and
//     ride under the current tile's MFMA+stores. Attacks the serial
//     load->sync->MFMA->store chain (r8: not stores; r12: not wave count).
//   - GEMM numerics unchanged: fp16 MFMA 16x16x32, fp32 accum; layer1 fp32
//     input, layer2 fp16 h1 (bit-identical, -25.6MB).
//   - Aggregation: EXACT round-1 form (proven 68.5us @ 89% VALUBusy):
//     one wave per node, 4 edges/iter, records 4 ahead / gathers 2 ahead,
//     dynamic loop, cvt_h2+fmaf body (r2-r5: asm/unroll degrade scheduling).
// ---------------------------------------------------------------------------

typedef _Float16 half8 __attribute__((ext_vector_type(8)));
typedef float floatx4 __attribute__((ext_vector_type(4)));

__global__ __launch_bounds__(256) void bucket_hist_sum(
    const int* __restrict__ dst, const float* __restrict__ ew,
    int* __restrict__ bcnt, float* __restrict__ sumbuf, int E) {
    __shared__ int h[256];
    h[threadIdx.x] = 0;
    __syncthreads();
    float s = 0.f;
    for (int i = blockIdx.x * blockDim.x + threadIdx.x; i < E; i += gridDim.x * blockDim.x) {
        atomicAdd(&h[dst[i] >> 8], 1);
        s += ew[i];
    }
#pragma unroll
    for (int off = 1; off <= 32; off <<= 1)
        s += __shfl_xor(s, off, 64);
    if ((threadIdx.x & 63) == 0)
        atomicAdd(sumbuf, s);
    __syncthreads();
    int v = h[threadIdx.x];
    if (v) atomicAdd(&bcnt[threadIdx.x], v);
}

// Partition edges into 256-node buckets. 1024 threads x 8 edges (r16:
// bigger per-block bucket chunks -> less srec write amplification).
// Absorbs bucket_scan (redundant LDS scan of bcnt; bcur is a ZERO-based
// relative cursor). Block 0 publishes bbase for build_csr.
__global__ __launch_bounds__(1024) void partition_kernel(
    const int* __restrict__ src, const int* __restrict__ dst, const float* __restrict__ ew,
    const int* __restrict__ bcnt, int* __restrict__ bcur, int* __restrict__ bbase,
    int2* __restrict__ srec, int E, int NBK) {
    __shared__ int ex[256];
    __shared__ int h[256];
    __shared__ int gb[256];
    const int t = threadIdx.x;                 // 0..1023

    // redundant exclusive scan of bcnt (replaces bucket_scan kernel)
    if (t < 256) ex[t] = (t < NBK) ? bcnt[t] : 0;
    __syncthreads();
    for (int off = 1; off < 256; off <<= 1) {
        int y = 0;
        if (t < 256 && t >= off) y = ex[t - off];
        __syncthreads();
        if (t < 256) ex[t] += y;
        __syncthreads();
    }
    if (blockIdx.x == 0 && t <= NBK)
        bbase[t] = (t < 256) ? (ex[t] - ((t < NBK) ? bcnt[t] : 0))
                             : ex[255];       // t == 256 (only if NBK == 256)
    if (t < 256) h[t] = 0;
    __syncthreads();

    const int base = blockIdx.x * 8192;
    int d[8], sv[8];
    float wv[8];
#pragma unroll
    for (int j = 0; j < 8; j++) {
        int i = base + t + j * 1024;
        if (i < E) {
            d[j] = dst[i];
            sv[j] = src[i];
            wv[j] = ew[i];
            atomicAdd(&h[d[j] >> 8], 1);
        } else {
            d[j] = -1;
        }
    }
    __syncthreads();
    if (t < 256) {
        int cntt = h[t];
        int exb = ex[t] - ((t < NBK) ? bcnt[t] : 0);
        if (cntt) gb[t] = exb + atomicAdd(&bcur[t], cntt);
        h[t] = 0;
    }
    __syncthreads();
#pragma unroll
    for (int j = 0; j < 8; j++) {
        if (d[j] >= 0) {
            int b = d[j] >> 8;
            int r = atomicAdd(&h[b], 1);
            int pos = gb[b] + r;
            // pack src (bits 0..19) | (dst&255) << 20
            srec[pos] = make_int2(sv[j] | ((d[j] & 255) << 20), __float_as_int(wv[j]));
        }
    }
}

// Fused dst_hist + scan1 + scan3 + refine (r15). Per bucket b:
//   1. LDS histogram of the bucket's records (4-way privatized).
//   2. Block-local scan of (deg+1); global base is CLOSED-FORM:
//      bbase[b] + 256*b (every node contributes exactly 1 self-loop).
//   3. Write rowp, self-loop record, init LDS cursors.
//   4. Scatter the bucket's edges into crec (srec slab is L2-hot from 1).
// All block-local -- no cross-block sync (r9 crash class excluded).
__global__ __launch_bounds__(1024) void build_csr_kernel(
    const int2* __restrict__ srec, const int* __restrict__ bbase,
    const float* __restrict__ sumbuf, int* __restrict__ rowp,
    int2* __restrict__ crec, int N, int E) {
    __shared__ int h4[4][256];
    __shared__ int sc[256];
    __shared__ int cur[256];
    const int t = threadIdx.x;            // 0..1023
    const int grp = t >> 8, sub = t & 255;
    h4[grp][sub] = 0;
    __syncthreads();
    const int b = blockIdx.x;
    const int e0 = bbase[b], e1 = bbase[b + 1];
    for (int i = e0 + t; i < e1; i += 1024)
        atomicAdd(&h4[grp][(srec[i].x >> 20) & 255], 1);
    __syncthreads();
    int deg = 0;
    if (t < 256) {
        deg = h4[0][t] + h4[1][t] + h4[2][t] + h4[3][t];
        int node = (b << 8) + t;
        sc[t] = (node < N) ? (deg + 1) : 0;
    }
    __syncthreads();
    for (int off = 1; off < 256; off <<= 1) {     // inclusive scan (256 lanes)
        int y = 0;
        if (t < 256 && t >= off) y = sc[t - off];
        __syncthreads();
        if (t < 256) sc[t] += y;
        __syncthreads();
    }
    const int base = bbase[b] + (b << 8);
    if (t < 256) {
        int node = (b << 8) + t;
        if (node < N) {
            int rp = base + sc[t] - (deg + 1);    // exclusive position
            rowp[node] = rp;
            cur[t] = rp;
            crec[rp + deg] = make_int2(node, __float_as_int(sumbuf[0] * (1.0f / (float)E)));
            if (node == N - 1) rowp[N] = E + N;
        }
    }
    __syncthreads();
    for (int i = e0 + t; i < e1; i += 1024) {
        int2 rec = srec[i];
        int dlow = (rec.x >> 20) & 255;
        int pos = atomicAdd(&cur[dlow], 1);
        crec[pos] = make_int2(rec.x & 0xFFFFF, rec.y);
    }
}

// ---------------------------------------------------------------------------
// Pre-pack BOTH layers' W = [Wa | Wb] into fragment-ordered fp16 (one launch)
// and zero bcnt[0..259] + bcur[0..259].
// ---------------------------------------------------------------------------
__global__ __launch_bounds__(256) void prep_w2_kernel(
    const float* __restrict__ Wa1, const float* __restrict__ Wb1,
    const float* __restrict__ Wa2, const float* __restrict__ Wb2,
    _Float16* __restrict__ Wh1, _Float16* __restrict__ Wh2,
    int* __restrict__ bcnt, int* __restrict__ bcur) {
    const int bid = blockIdx.x;                 // 0..255
    if (bid == 0 && threadIdx.x < 260) bcnt[threadIdx.x] = 0;
    if (bid == 1 && threadIdx.x < 260) bcur[threadIdx.x] = 0;
    const int sel = bid >> 7;
    const float* Wa = sel ? Wa2 : Wa1;
    const float* Wb = sel ? Wb2 : Wb1;
    _Float16* Wh = sel ? Wh2 : Wh1;
    int tid = (bid & 127) * 256 + threadIdx.x;  // 0 .. 32767
    int j = tid & 7;
    int lane = (tid >> 3) & 63;
    int f = tid >> 9;                           // 0..63
    int kk = f & 3;
    int ct = f >> 2;                            // 0..15
    int col = ct * 16 + (lane & 15);
    int k = kk * 32 + ((lane >> 4) << 3) + j;
    float v = (col < 128) ? Wa[k * 128 + col] : Wb[k * 128 + (col - 128)];
    Wh[tid] = (_Float16)v;
}

// ---------------------------------------------------------------------------
// Dual GEMM on the matrix pipe: Yh = half(X@Wa) [Nx128], Yb = X@Wb [Nx128].
// r17: multi-tile with register prefetch (T14). Grid = ceil(NT/2); each
// block strides tiles (tile, tile+G). W fragments load once per block.
// Per tile: barrier -> ds_write(staged regs) -> barrier -> issue next
// tile's global loads -> ds_read + 64 MFMA + stores. Next tile's HBM
// latency hides under current tile's compute.
// Swapped operands (D = W^T X^T); r6 scattered-store epilogue (r8 lesson).
// ---------------------------------------------------------------------------
template <typename T>
__global__ __launch_bounds__(256) void gemm_mfma_kernel(
    const T* __restrict__ X, const _Float16* __restrict__ Wh,
    __half* __restrict__ Yh, float* __restrict__ Yb, int N, int NT) {
    __shared__ _Float16 Xs[64 * 128];            // 16 KB, swizzled
    const int tid = threadIdx.x;
    const int lane = tid & 63;
    const int w = tid >> 6;

    // W fragments -> registers, once per block (16 x coalesced 16B/lane)
    half8 wf[4][4];
#pragma unroll
    for (int ct = 0; ct < 4; ct++)
#pragma unroll
        for (int kk = 0; kk < 4; kk++)
            wf[ct][kk] = *(const half8*)(Wh + (size_t)(((w * 4 + ct) * 4 + kk) * 512 + lane * 8));

    // register staging for one tile
    float4 pf[8];                                // fp32 path (32 VGPR)
    int4   pg[4];                                // fp16 path (16 VGPR)

    auto prefetch = [&](int tile) {
        if (tile >= NT) return;
        const int rb = tile * 64;
        if constexpr (std::is_same<T, float>::value) {
#pragma unroll
            for (int it = 0; it < 8; it++) {
                int c = it * 256 + tid;
                int row = c >> 5;
                int f4 = c & 31;
                pf[it] = make_float4(0.f, 0.f, 0.f, 0.f);
                if (rb + row < N)
                    pf[it] = ((const float4*)X)[(size_t)(rb + row) * 32 + f4];
            }
        } else {
#pragma unroll
            for (int it = 0; it < 4; it++) {
                int c = it * 256 + tid;
                int row = c >> 4;
                int f16 = c & 15;
                pg[it] = make_int4(0, 0, 0, 0);
                if (rb + row < N)
                    pg[it] = ((const int4*)X)[(size_t)(rb + row) * 16 + f16];
            }
        }
    };

    prefetch(blockIdx.x);

    for (int tile = blockIdx.x; tile < NT; tile += gridDim.x) {
        const int rb = tile * 64;
        __syncthreads();                         // prev tile's ds_reads done
        // staged regs -> swizzled LDS
        if constexpr (std::is_same<T, float>::value) {
#pragma unroll
            for (int it = 0; it < 8; it++) {
                int c = it * 256 + tid;
                int row = c >> 5;
                int f4 = c & 31;
                float4 v = pf[it];
                _Float16 h[4] = {(_Float16)v.x, (_Float16)v.y, (_Float16)v.z, (_Float16)v.w};
                int byteoff = row * 256 + ((f4 * 8) ^ ((row & 7) << 4));
                *(uint2*)((char*)Xs + byteoff) = *(uint2*)h;
            }
        } else {
#pragma unroll
            for (int it = 0; it < 4; it++) {
                int c = it * 256 + tid;
                int row = c >> 4;
                int f16 = c & 15;
                int byteoff = row * 256 + ((f16 * 16) ^ ((row & 7) << 4));
                *(int4*)((char*)Xs + byteoff) = pg[it];
            }
        }
        __syncthreads();
        // issue next tile's loads; they complete under MFMA+stores below
        prefetch(tile + gridDim.x);

        floatx4 acc[4][4];
#pragma unroll
        for (int ct = 0; ct < 4; ct++)
#pragma unroll
            for (int rt = 0; rt < 4; rt++)
                acc[ct][rt] = (floatx4){0.f, 0.f, 0.f, 0.f};

#pragma unroll
        for (int kk = 0; kk < 4; kk++) {
            half8 xf[4];
#pragma unroll
            for (int rt = 0; rt < 4; rt++) {
                int row = rt * 16 + (lane & 15);
                int kb = kk * 64 + ((lane >> 4) << 4);
                int off = row * 256 + (kb ^ ((row & 7) << 4));
                xf[rt] = *(const half8*)((const char*)Xs + off);
            }
#pragma unroll
            for (int ct = 0; ct < 4; ct++)
#pragma unroll
                for (int rt = 0; rt < 4; rt++)
                    acc[ct][rt] = __builtin_amdgcn_mfma_f32_16x16x32_f16(
                        wf[ct][kk], xf[rt], acc[ct][rt], 0, 0, 0);
        }

        // Epilogue: lane owns row rb+rt*16+(lane&15), cols gct*16+(lane>>4)*4..
        const int rsub = lane & 15;
        const int c4 = (lane >> 4) << 2;
#pragma unroll
        for (int ct = 0; ct < 4; ct++) {
            int gct = w * 4 + ct;
#pragma unroll
            for (int rt = 0; rt < 4; rt++) {
                int row = rb + rt * 16 + rsub;
                if (row < N) {
                    floatx4 a = acc[ct][rt];
                    if (gct < 8) {
                        int col = gct * 16 + c4;
                        __half2 hp[2];
                        hp[0] = __floats2half2_rn(a[0], a[1]);
                        hp[1] = __floats2half2_rn(a[2], a[3]);
                        *(uint2*)(Yh + (size_t)row * 128 + col) = *(uint2*)hp;
                    } else {
                        int col = (gct - 8) * 16 + c4;
                        *(float4*)(Yb + (size_t)row * 128 + col) =
                            make_float4(a[0], a[1], a[2], a[3]);
                    }
                }
            }
        }
    }
}

// DPP partial-sum step within quads on the VALU pipe.
template <int CTRL>
__device__ __forceinline__ float dpp_sum_step(float v) {
    int t = __builtin_amdgcn_update_dpp(0, __float_as_int(v), CTRL, 0xF, 0xF, true);
    return v + __int_as_float(t);
}

__device__ __forceinline__ float2 cvt_h2(unsigned u) {
    __half2 h = *(__half2*)&u;
    return __half22float2(h);
}

// One wave per node; 4 edges/iteration.
// lane l: g=l>>4 (edge slot), q=l&15 -> channels 8q..8q+7 (head q>>2).
// Pipeline: records 4 iters ahead, gathers 2 iters ahead.  (round-1 exact)
// mode 0: ELU output stored as fp16 (h1), packed via __half2 pairs;
// mode 1: fp32 final output.
__global__ __launch_bounds__(256) void agg_kernel(
    const __half* __restrict__ xlh, const float* __restrict__ xr,
    const int* __restrict__ rowp, const int2* __restrict__ crec,
    const float* __restrict__ We, const float* __restrict__ att, const float* __restrict__ bias,
    void* __restrict__ out, int N, int mode) {
    const int wid = threadIdx.x >> 6;
    const int lane = threadIdx.x & 63;
    const int n = blockIdx.x * 4 + wid;
    if (n >= N) return;
    const int g = lane >> 4;
    const int q = lane & 15;
    const int c0 = q << 3;                         // channel base, 8 per lane
    const float LOG2E = 1.4426950408889634f;

    float we[8], xv[8], at6[8], at4[8];
    {
        float4 wA = *(const float4*)(We + c0);
        float4 wB = *(const float4*)(We + c0 + 4);
        we[0]=wA.x; we[1]=wA.y; we[2]=wA.z; we[3]=wA.w;
        we[4]=wB.x; we[5]=wB.y; we[6]=wB.z; we[7]=wB.w;
        float4 rA = *(const float4*)(xr + (size_t)n * 128 + c0);
        float4 rB = *(const float4*)(xr + (size_t)n * 128 + c0 + 4);
        xv[0]=rA.x; xv[1]=rA.y; xv[2]=rA.z; xv[3]=rA.w;
        xv[4]=rB.x; xv[5]=rB.y; xv[6]=rB.z; xv[7]=rB.w;
        float4 aA = *(const float4*)(att + c0);
        float4 aB = *(const float4*)(att + c0 + 4);
        float av[8] = {aA.x, aA.y, aA.z, aA.w, aB.x, aB.y, aB.z, aB.w};
#pragma unroll
        for (int c = 0; c < 8; c++) {
            at6[c] = 0.6f * LOG2E * av[c];
            at4[c] = 0.4f * LOG2E * av[c];
        }
    }

    float acc[8];
#pragma unroll
    for (int c = 0; c < 8; c++) acc[c] = 0.f;
    float l0 = 0.f;

    const int e0 = __builtin_amdgcn_readfirstlane(rowp[n]);
    const int e1 = __builtin_amdgcn_readfirstlane(rowp[n + 1]);
    const int cnt = e1 - e0;
    const int T = (cnt + 3) >> 2;

    auto recload = [&](int i) -> int2 {
        int idx = e0 + (i << 2) + g;
        idx = (idx < e1 - 1) ? idx : (e1 - 1);     // clamp (always valid)
        return crec[idx];
    };
    auto gatherx = [&](int s) -> int4 {            // 8 halves = 16B
        return *(const int4*)(xlh + (size_t)s * 128 + c0);
    };
    auto process = [&](int4 xh, float w, bool valid) {
        float2 x01 = cvt_h2(xh.x), x23 = cvt_h2(xh.y);
        float2 x45 = cvt_h2(xh.z), x67 = cvt_h2(xh.w);
        float xs[8] = {x01.x, x01.y, x23.x, x23.y, x45.x, x45.y, x67.x, x67.y};
        float p = 0.f;
#pragma unroll
        for (int c = 0; c < 8; c++) {
            float z = xs[c] + fmaf(w, we[c], xv[c]);
            p = fmaf(at6[c], z, fmaf(at4[c], fabsf(z), p));  // leaky folded
        }
        p = dpp_sum_step<0xB1>(p);    // quad_perm [1,0,3,2]
        p = dpp_sum_step<0x4E>(p);    // quad_perm [2,3,0,1]  -> per-head sum
        float qe = valid ? __builtin_amdgcn_exp2f(p) : 0.f;
        l0 += qe;
#pragma unroll
        for (int c = 0; c < 8; c++) acc[c] = fmaf(qe, xs[c], acc[c]);
    };

    // rolling pipeline: records 4 iters ahead, gathers 2 ahead
    int2 r0 = recload(0), r1 = recload(1), r2 = recload(2), r3 = recload(3);
    int4 x0 = gatherx(r0.x), x1 = gatherx(r1.x);
    for (int i = 0; i < T; ++i) {
        int2 r4 = recload(i + 4);
        int4 x2 = gatherx(r2.x);
        process(x0, __int_as_float(r0.y), (e0 + (i << 2) + g) < e1);
        r0 = r1; r1 = r2; r2 = r3; r3 = r4;
        x0 = x1; x1 = x2;
    }

    // combine the 4 edge groups
    l0 += __shfl_xor(l0, 16, 64);
    l0 += __shfl_xor(l0, 32, 64);
#pragma unroll
    for (int c = 0; c < 8; c++) {
        acc[c] += __shfl_xor(acc[c], 16, 64);
        acc[c] += __shfl_xor(acc[c], 32, 64);
    }
    float rdenom = 1.0f / (l0 + 1e-16f);
    float r[8];
#pragma unroll
    for (int c = 0; c < 8; c++) r[c] = acc[c] * rdenom;

    if (mode == 0) {
        if (g == 0) {
            float4 bA = *(const float4*)(bias + c0);
            float4 bB = *(const float4*)(bias + c0 + 4);
            float bv[8] = {bA.x, bA.y, bA.z, bA.w, bB.x, bB.y, bB.z, bB.w};
            float o[8];
#pragma unroll
            for (int c = 0; c < 8; c++) {
                float v = r[c] + bv[c];
                o[c] = (v > 0.f) ? v : (__expf(v) - 1.f);   // ELU
            }
            __half2 p0 = __floats2half2_rn(o[0], o[1]);
            __half2 p1 = __floats2half2_rn(o[2], o[3]);
            __half2 p2 = __floats2half2_rn(o[4], o[5]);
            __half2 p3 = __floats2half2_rn(o[6], o[7]);
            int4 pk = make_int4(*(int*)&p0, *(int*)&p1, *(int*)&p2, *(int*)&p3);
            *(int4*)((__half*)out + (size_t)n * 128 + c0) = pk;
        }
    } else {
#pragma unroll
        for (int c = 0; c < 8; c++) {
            r[c] += __shfl_xor(r[c], 4, 64);
            r[c] += __shfl_xor(r[c], 8, 64);
        }
        if (lane < 4) {
            int w0 = lane << 3;
            float4 bA = *(const float4*)(bias + w0);
            float4 bB = *(const float4*)(bias + w0 + 4);
            float bv[8] = {bA.x, bA.y, bA.z, bA.w, bB.x, bB.y, bB.z, bB.w};
            float o[8];
#pragma unroll
            for (int c = 0; c < 8; c++) o[c] = 0.25f * r[c] + bv[c];
            float* op = (float*)out + (size_t)n * 32 + w0;
            *(float4*)op       = make_float4(o[0], o[1], o[2], o[3]);
            *(float4*)(op + 4) = make_float4(o[4], o[5], o[6], o[7]);
        }
    }
}

extern "C" void kernel_launch(void* const* d_in, const int* in_sizes, int n_in,
                              void* d_out, int out_size, void* d_ws, size_t ws_size,
                              hipStream_t stream) {
    const float* x    = (const float*)d_in[0];
    const int*  eidx  = (const int*)d_in[1];
    const float* ew   = (const float*)d_in[2];
    const float* Wl1  = (const float*)d_in[3];
    const float* Wr1  = (const float*)d_in[4];
    const float* We1  = (const float*)d_in[5];
    const float* att1 = (const float*)d_in[6];
    const float* b1   = (const float*)d_in[7];
    const float* Wl2  = (const float*)d_in[8];
    const float* Wr2  = (const float*)d_in[9];
    const float* We2  = (const float*)d_in[10];
    const float* att2 = (const float*)d_in[11];
    const float* b2   = (const float*)d_in[12];

    const int N = in_sizes[0] / 128;
    const int E = in_sizes[1] / 2;
    const int* src = eidx;
    const int* dst = eidx + E;
    const int NBK = (N + 255) >> 8;
    const int NT  = (N + 63) / 64;
    const int GG  = (NT + 1) / 2;              // 2 tiles per block

    char* p = (char*)d_ws;
    auto alloc = [&](size_t bytes) -> void* {
        void* r = (void*)p;
        p += (bytes + 255) & ~(size_t)255;
        return r;
    };
    __half* xlh   = (__half*)alloc((size_t)N * 128 * sizeof(__half));
    float* xr     = (float*)alloc((size_t)N * 128 * sizeof(float));
    __half* h1h   = (__half*)alloc((size_t)N * 128 * sizeof(float));  // fp16 used; fp32-sized (srec alias)
    int2*  crec   = (int2*)alloc((size_t)(E + N + 64) * sizeof(int2));
    int*   rowp   = (int*)alloc((size_t)(N + 1) * sizeof(int));
    int*   bcnt   = (int*)alloc(260 * sizeof(int));
    float* sumbuf = (float*)(bcnt + 256);
    int*   bbase  = (int*)alloc(260 * sizeof(int));
    int*   bcur   = (int*)alloc(260 * sizeof(int));
    _Float16* Wh1 = (_Float16*)alloc(32768 * sizeof(_Float16));
    _Float16* Wh2 = (_Float16*)alloc(32768 * sizeof(_Float16));
    int2*  srec   = (int2*)h1h;                     // staging aliased into h1

    // weight pre-pack (both layers) + zeroing of bcnt/sumbuf/bcur
    prep_w2_kernel<<<256, 256, 0, stream>>>(Wl1, Wr1, Wl2, Wr2, Wh1, Wh2,
                                            bcnt, bcur);

    bucket_hist_sum<<<1024, 256, 0, stream>>>(dst, ew, bcnt, sumbuf, E);
    partition_kernel<<<(E + 8191) / 8192, 1024, 0, stream>>>(
        src, dst, ew, bcnt, bcur, bbase, srec, E, NBK);
    build_csr_kernel<<<NBK, 1024, 0, stream>>>(srec, bbase, sumbuf, rowp,
                                               crec, N, E);

    // Layer 1 (fp32 input)
    gemm_mfma_kernel<float><<<GG, 256, 0, stream>>>(x, Wh1, xlh, xr, N, NT);
    agg_kernel<<<(N + 3) / 4, 256, 0, stream>>>(xlh, xr, rowp, crec,
                                                We1, att1, b1, (void*)h1h, N, 0);
    // Layer 2 (fp16 input)
    gemm_mfma_kernel<_Float16><<<GG, 256, 0, stream>>>(
        (const _Float16*)h1h, Wh2, xlh, xr, N, NT);
    agg_kernel<<<(N + 3) / 4, 256, 0, stream>>>(xlh, xr, rowp, crec,
                                                We2, att2, b2, d_out, N, 1);
}